// Round 7
// baseline (203.833 us; speedup 1.0000x reference)
//
#include <hip/hip_runtime.h>
#include <hip/hip_bf16.h>
#include <stdint.h>

// Problem constants (from reference)
#define H   128
#define NM  5000
#define NO  100000
#define EA  1000000
#define EC  500000
#define ET  1000000
#define EL  500000

typedef __hip_bfloat16 bf16;
typedef float f32x4 __attribute__((ext_vector_type(4)));
typedef short short8 __attribute__((ext_vector_type(8)));

// R7 structure:
//   Z  : zero workspace + dtype flag                      (66 blocks, ~3us)
//   K0 : counts, WIDE (quarantines atomic/L2 damage)      (576 blocks, ~10us)
//   K1 : gine | sage | means | warm  (R5's measured-44us partition)
//   K2 : final (2 blocks)
// R6 lesson: counts co-resident with gine for K1's whole life cost +7us via
// L2 line ping-pong (WRITE_SIZE 0.78->19MB) + x_o eviction. Quarantine them.
#define CM_BLK 64
#define CO_BLK 512
#define K0_BLOCKS (CM_BLK + CO_BLK)

#define B_GA 1024
#define B_GC 512
#define B_TV 256
#define B_LG 128
#define B_MN 48
#define B_WM 6
#define K1_BLOCKS (B_GA + B_GC + B_TV + B_LG + B_MN + B_WM)   // 1974 <= 2048

// zero kernel geometry: range A=[0,430080) cnt arrays, B=[430592,447776) parts.
#define ZA_U4 26880
#define ZB_OFF 430592
#define ZB_U4 1074
#define Z_BLOCKS 66

struct Par {
    const void *x_m, *x_o, *ea_a, *ea_c;
    const int *ei_a, *ei_c, *ei_tv, *ei_log;
    const void *Wm, *bm, *Wo, *bo;
    const void *Wn_a, *bn_a, *We_a, *be_a;
    const void *Wn_c, *bn_c, *We_c, *be_c;
    const void *Wl_tv, *bl_tv, *Wr_tv, *Wl_log, *bl_log, *Wr_log;
    int *cnt_m, *cnt_o;
    float *part_a, *part_c;        // [16][128] replicated accumulators
    float *part_tv, *part_lg;      // [8][8]
    float *part_mn_m, *part_mn_o;  // [8][4]
    float *sink;
    char *wsbase;
    int *flagw;
    const int *flag;
    void *out;
};

// ---- dtype-flexible loads ----
template<bool ISF32>
__device__ __forceinline__ float ldf(const void* p, int i) {
    if constexpr (ISF32) return ((const float*)p)[i];
    else                 return __bfloat162float(((const bf16*)p)[i]);
}

__device__ __forceinline__ float bflo(uint32_t v) {
    union { uint32_t u; float f; } c; c.u = v << 16; return c.f;
}
__device__ __forceinline__ float bfhi(uint32_t v) {
    union { uint32_t u; float f; } c; c.u = v & 0xFFFF0000u; return c.f;
}

__device__ __forceinline__ uint32_t pack2(float a, float b) {
    union { bf16 h; uint16_t u; } ca, cb;
    ca.h = __float2bfloat16(a); cb.h = __float2bfloat16(b);
    return (uint32_t)ca.u | ((uint32_t)cb.u << 16);
}

__device__ __forceinline__ uint16_t bfbits(float a) {
    union { bf16 h; uint16_t u; } c; c.h = __float2bfloat16(a); return c.u;
}

template<bool ISF32>
__device__ __forceinline__ float4 ld4(const void* p, int row) {
    if constexpr (ISF32) return ((const float4*)p)[row];
    else {
        const uint2 t = ((const uint2*)p)[row];
        float4 r; r.x = bflo(t.x); r.y = bfhi(t.x); r.z = bflo(t.y); r.w = bfhi(t.y);
        return r;
    }
}

__device__ __forceinline__ float wred(float v) {
#pragma unroll
    for (int o = 32; o; o >>= 1) v += __shfl_down(v, o, 64);
    return v;
}

// ---- Z: zero workspace + dtype-detect flag ----
__global__ __launch_bounds__(256) void zero_kernel(const Par p) {
    const int t = threadIdx.x;
    const int b = blockIdx.x;
    const uint4 z = (uint4){0, 0, 0, 0};
    if (b < 64) {
        uint4* a = (uint4*)p.wsbase;
        for (int i = b * 256 + t; i < ZA_U4; i += 64 * 256) a[i] = z;
    } else if (b == 64) {
        uint4* bp = (uint4*)(p.wsbase + ZB_OFF);
        for (int i = t; i < ZB_U4; i += 256) bp[i] = z;
    } else {
        // dtype detect: f32 inputs show 0xFF exponent-field patterns in the
        // mantissa-low u16 halves; bf16 N(0,1) never does.
        __shared__ int fl;
        if (t == 0) fl = 0;
        __syncthreads();
        int local = 0;
        const uint16_t* xm = (const uint16_t*)p.x_m;
        for (int i = t; i < 15000; i += 256)
            if (((xm[i] >> 7) & 0xFF) == 0xFF) local = 1;
        if (local) atomicOr(&fl, 1);
        __syncthreads();
        if (t == 0) *p.flagw = fl;
    }
}

// ---- K0: counts, wide. cnt arrays pre-zeroed by Z. ----
// cnt_m: 64 LDS-hist blocks (2x16-bit packed counters, 10 KB), ~30 scan
// iterations each, then rotated global atomic flush (max/bin 15625 < 2^16).
// cnt_o: 512 blocks, ~1 int4 iteration each, direct global atomics.
__global__ __launch_bounds__(256) void count_kernel(const Par p) {
    __shared__ uint32_t hist[2500];
    const int t = threadIdx.x;
    const int b = blockIdx.x;
    if (b < CM_BLK) {
        for (int i = t; i < 2500; i += 256) hist[i] = 0;
        __syncthreads();
        const int2* dst2 = (const int2*)(p.ei_tv + ET);
        for (int i = b * 256 + t; i < ET / 2; i += CM_BLK * 256) {
            const int2 d = dst2[i];
            atomicAdd(&hist[d.x >> 1], 1u << ((d.x & 1) * 16));
            atomicAdd(&hist[d.y >> 1], 1u << ((d.y & 1) * 16));
        }
        __syncthreads();
        const int rot = (b * 157) % 2500;
        for (int i = t; i < 2500; i += 256) {
            int j = i + rot; if (j >= 2500) j -= 2500;
            const uint32_t v = hist[j];
            const int lo = (int)(v & 0xFFFFu), hi = (int)(v >> 16);
            if (lo) atomicAdd(&p.cnt_m[2 * j], lo);
            if (hi) atomicAdd(&p.cnt_m[2 * j + 1], hi);
        }
    } else {
        const int rb = b - CM_BLK;
        const int4* d4 = (const int4*)(p.ei_log + EL);
        for (int i = rb * 256 + t; i < EL / 4; i += CO_BLK * 256) {
            const int4 d = d4[i];
            atomicAdd(&p.cnt_o[d.x], 1);
            atomicAdd(&p.cnt_o[d.y], 1);
            atomicAdd(&p.cnt_o[d.z], 1);
            atomicAdd(&p.cnt_o[d.w], 1);
        }
    }
}

// ---- GINE via MFMA, occupancy-safe (channels split across waves) ----
// Granule = 256 edges staged once per block (bf16, double-buffered).
// F[256][8]: features + edge-attrs + constant-1 column (bias = W-row KT,
// zero-padded rows contribute 0). Wave w owns channels [32w, 32w+32).
// Output: per-block channel sums atomicAdd'ed into a replicated 128-vector.
// bf16 inputs stage RAW BITS (integer packs only, no f32 round-trip).
template<int FIN, int ED, bool ISF32>
__device__ __forceinline__ void gine_body(
    const int* __restrict__ src, const void* __restrict__ ea,
    const void* __restrict__ x, const void* __restrict__ We,
    const void* __restrict__ be, const void* __restrict__ Wx,
    const void* __restrict__ bx, float* __restrict__ partv,
    int E, int relb, int nblk, uint4* stage /* [2][256] */)
{
    constexpr int KT = FIN + ED;          // bias row at k=KT; KT+1 <= 8
    const int tid = threadIdx.x;
    const int lane = tid & 63;
    const int wv = tid >> 6;
    const int q = lane >> 4;
    const int col = lane & 15;

    // B fragments for this wave's 2 N-tiles; only quad 0 holds nonzeros (K<=7).
    short8 bfr[2];
#pragma unroll
    for (int nt = 0; nt < 2; ++nt) {
        const int ch = wv * 32 + nt * 16 + col;
        short8 s = (short8)0;
#pragma unroll
        for (int j = 0; j < 8; ++j) {
            const int k = q * 8 + j;
            float w = 0.f;
            if (k < FIN)       w = ldf<ISF32>(Wx, k * H + ch);
            else if (k < KT)   w = ldf<ISF32>(We, (k - FIN) * H + ch);
            else if (k == KT)  w = ldf<ISF32>(bx, ch) + ldf<ISF32>(be, ch);
            s[j] = (short)bfbits(w);
        }
        bfr[nt] = s;
    }
    f32x4 acc0 = (f32x4)0.f, acc1 = (f32x4)0.f;
    const f32x4 zero4 = (f32x4)0.f;

    const int G = (E + 255) >> 8;
    const int chunk = (G + nblk - 1) / nblk;
    const int g0 = relb * chunk;
    const int g1 = min(g0 + chunk, G);
    for (int g = g0; g < g1; ++g) {
        const int buf = g & 1;
        const int base = g << 8;
        const int ecnt = min(256, E - base);
        uint4 pk = (uint4){0, 0, 0, 0};
        if (tid < ecnt) {
            const int ej = base + tid;
            const int s = src[ej];
            if constexpr (!ISF32) {
                // raw-bit path: no float conversions at all
                const uint16_t* xb = (const uint16_t*)x;
                const uint16_t* eb = (const uint16_t*)ea;
                if constexpr (FIN == 4) {          // x_o row = 4 bf16 = uint2
                    const uint2 xr = ((const uint2*)x)[s];
                    pk.x = xr.x; pk.y = xr.y;
                } else {                            // FIN == 3
                    const uint32_t x0 = xb[s * 3], x1 = xb[s * 3 + 1], x2 = xb[s * 3 + 2];
                    pk.x = x0 | (x1 << 16);
                    pk.y = x2;                      // high half filled below
                }
                if constexpr (FIN == 3 && ED == 3) {        // gine_a: KT=6
                    const uint32_t e0 = eb[ej * 3], e1 = eb[ej * 3 + 1], e2 = eb[ej * 3 + 2];
                    pk.y |= e0 << 16;
                    pk.z = e1 | (e2 << 16);
                    pk.w = 0x00003F80u;             // f[6]=1.0, f[7]=0
                } else {                             // gine_c: FIN=4, ED=1, KT=5
                    const uint32_t e0 = eb[ej];
                    pk.z = e0 | (0x3F80u << 16);    // f[4]=ea, f[5]=1.0
                    pk.w = 0;
                }
            } else {
                float f[8];
#pragma unroll
                for (int k = 0; k < 8; ++k) f[k] = 0.f;
                if constexpr (FIN == 4) {
                    const float4 xv = ld4<true>(x, s);
                    f[0] = xv.x; f[1] = xv.y; f[2] = xv.z; f[3] = xv.w;
                } else {
#pragma unroll
                    for (int k = 0; k < FIN; ++k) f[k] = ldf<true>(x, s * FIN + k);
                }
#pragma unroll
                for (int k = 0; k < ED; ++k) f[FIN + k] = ldf<true>(ea, ej * ED + k);
                f[KT] = 1.0f;
                pk.x = pack2(f[0], f[1]); pk.y = pack2(f[2], f[3]);
                pk.z = pack2(f[4], f[5]); pk.w = pack2(f[6], f[7]);
            }
        }
        stage[buf * 256 + tid] = pk;
        __syncthreads();   // stage visible; also guards buf reuse (2 bufs)
        const uint4* st = stage + buf * 256;
#pragma unroll 4
        for (int mt = 0; mt < 16; ++mt) {
            union { short8 s; uint4 u; } au;
            au.u = (uint4){0, 0, 0, 0};
            if (lane < 16) au.u = st[mt * 16 + lane];   // exec-masked A-frag
            f32x4 d0 = __builtin_amdgcn_mfma_f32_16x16x32_bf16(au.s, bfr[0], zero4, 0, 0, 0);
            f32x4 d1 = __builtin_amdgcn_mfma_f32_16x16x32_bf16(au.s, bfr[1], zero4, 0, 0, 0);
            acc0 += __builtin_elementwise_max(d0, zero4);
            acc1 += __builtin_elementwise_max(d1, zero4);
        }
    }
    // fold: 4 regs (edge rows) + cross-quad -> channel sums on lanes 0..15
    float v0 = acc0[0] + acc0[1] + acc0[2] + acc0[3];
    v0 += __shfl_xor(v0, 16, 64);
    v0 += __shfl_xor(v0, 32, 64);
    float v1 = acc1[0] + acc1[1] + acc1[2] + acc1[3];
    v1 += __shfl_xor(v1, 16, 64);
    v1 += __shfl_xor(v1, 32, 64);
    if (lane < 16) {
        atomicAdd(&partv[wv * 32 + col], v0);
        atomicAdd(&partv[wv * 32 + 16 + col], v1);
    }
}

// ---- component sums of x over nodes ----
template<int FIN, bool ISF32>
__device__ __forceinline__ void mean_body(
    const void* __restrict__ x, float* __restrict__ partv, int N,
    int relb, int nblk, float* lds)
{
    const int stride = nblk * 256;
    float acc[FIN];
#pragma unroll
    for (int k = 0; k < FIN; ++k) acc[k] = 0.f;
    for (int n = relb * 256 + threadIdx.x; n < N; n += stride) {
        if constexpr (FIN == 4) {
            const float4 xv = ld4<ISF32>(x, n);
            acc[0] += xv.x; acc[1] += xv.y; acc[2] += xv.z; acc[3] += xv.w;
        } else {
#pragma unroll
            for (int k = 0; k < FIN; ++k) acc[k] += ldf<ISF32>(x, n * FIN + k);
        }
    }
#pragma unroll
    for (int k = 0; k < FIN; ++k) acc[k] = wred(acc[k]);
    if ((threadIdx.x & 63) == 0) {
        const int w = threadIdx.x >> 6;
#pragma unroll
        for (int k = 0; k < 4; ++k) lds[w * 4 + k] = (k < FIN) ? acc[k] : 0.f;
    }
    __syncthreads();
    if (threadIdx.x < 4)
        atomicAdd(&partv[threadIdx.x],
                  lds[threadIdx.x] + lds[4 + threadIdx.x]
                + lds[8 + threadIdx.x] + lds[12 + threadIdx.x]);
}

// ---- SAGE edge reduction, int4-batched ----
template<bool ISF32>
__device__ __forceinline__ void sage_body(
    const void* __restrict__ x, const int* __restrict__ src,
    const int* __restrict__ dst, const int* __restrict__ cnt,
    float* __restrict__ partv, int E, int relb, int nblk, float* lds)
{
    const int tid = threadIdx.x;
    const int nv = E >> 2;
    const int stride = nblk * 256;
    float a0 = 0.f, a1 = 0.f, a2 = 0.f, a3 = 0.f, aw = 0.f;
#pragma unroll 2
    for (int i = relb * 256 + tid; i < nv; i += stride) {
        const int4 s4 = ((const int4*)src)[i];
        const int4 d4 = ((const int4*)dst)[i];
        const int c0 = cnt[d4.x], c1 = cnt[d4.y], c2 = cnt[d4.z], c3 = cnt[d4.w];
        const float4 x0 = ld4<ISF32>(x, s4.x);
        const float4 x1 = ld4<ISF32>(x, s4.y);
        const float4 x2 = ld4<ISF32>(x, s4.z);
        const float4 x3 = ld4<ISF32>(x, s4.w);
        const float i0 = __builtin_amdgcn_rcpf((float)(c0 > 0 ? c0 : 1));
        const float i1 = __builtin_amdgcn_rcpf((float)(c1 > 0 ? c1 : 1));
        const float i2 = __builtin_amdgcn_rcpf((float)(c2 > 0 ? c2 : 1));
        const float i3 = __builtin_amdgcn_rcpf((float)(c3 > 0 ? c3 : 1));
        a0 = fmaf(i0, x0.x, a0); a1 = fmaf(i0, x0.y, a1); a2 = fmaf(i0, x0.z, a2); a3 = fmaf(i0, x0.w, a3); aw += i0;
        a0 = fmaf(i1, x1.x, a0); a1 = fmaf(i1, x1.y, a1); a2 = fmaf(i1, x1.z, a2); a3 = fmaf(i1, x1.w, a3); aw += i1;
        a0 = fmaf(i2, x2.x, a0); a1 = fmaf(i2, x2.y, a1); a2 = fmaf(i2, x2.z, a2); a3 = fmaf(i2, x2.w, a3); aw += i2;
        a0 = fmaf(i3, x3.x, a0); a1 = fmaf(i3, x3.y, a1); a2 = fmaf(i3, x3.z, a2); a3 = fmaf(i3, x3.w, a3); aw += i3;
    }
    a0 = wred(a0); a1 = wred(a1); a2 = wred(a2); a3 = wred(a3); aw = wred(aw);
    if ((tid & 63) == 0) {
        float* w5 = lds + (tid >> 6) * 5;
        w5[0] = a0; w5[1] = a1; w5[2] = a2; w5[3] = a3; w5[4] = aw;
    }
    __syncthreads();
    if (tid < 5)
        atomicAdd(&partv[tid], lds[tid] + lds[5 + tid] + lds[10 + tid] + lds[15 + tid]);
}

// ---- warm: stream final-kernel weights into L2/L3 ----
__device__ __forceinline__ void warm_body(const Par p, int rb, bool f32, float* lds) {
    const void* w[6] = {p.Wn_a, p.Wn_c, p.Wl_tv, p.Wr_tv, p.Wl_log, p.Wr_log};
    const uint4* u = (const uint4*)w[rb];
    const int n16 = (f32 ? (H * H * 4) : (H * H * 2)) / 16;
    uint32_t s = 0;
    for (int i = threadIdx.x; i < n16; i += 256) {
        const uint4 v = u[i];
        s ^= v.x ^ v.y ^ v.z ^ v.w;
    }
    lds[threadIdx.x] = (float)(s & 1);
    __syncthreads();
    if (threadIdx.x == 0) {
        float acc = 0.f;
        for (int i = 0; i < 256; ++i) acc += lds[i];
        p.sink[rb] = acc;   // dummy sink, never read
    }
}

// ---- K1: gine_a | gine_c | sage_tv | sage_log | means | warm ----
// (R5's measured-44us partition; counts now live in K0, sage reads them
// across the kernel boundary.)
template<bool ISF32>
__device__ __forceinline__ void k1_body(const Par p, uint4* stage, float* red) {
    const int b = blockIdx.x;
    const int r16 = b & 15;
    const int r8 = b & 7;
    if (b < B_GA) {
        gine_body<3, 3, ISF32>(p.ei_a, p.ea_a, p.x_m, p.We_a, p.be_a, p.Wm, p.bm,
                               p.part_a + r16 * H, EA, b, B_GA, stage);
    } else if (b < B_GA + B_GC) {
        const int rb = b - B_GA;
        gine_body<4, 1, ISF32>(p.ei_c, p.ea_c, p.x_o, p.We_c, p.be_c, p.Wo, p.bo,
                               p.part_c + r16 * H, EC, rb, B_GC, stage);
    } else if (b < B_GA + B_GC + B_TV) {
        const int rb = b - (B_GA + B_GC);
        sage_body<ISF32>(p.x_o, p.ei_tv, p.ei_tv + ET, p.cnt_m,
                         p.part_tv + r8 * 8, ET, rb, B_TV, red);
    } else if (b < B_GA + B_GC + B_TV + B_LG) {
        const int rb = b - (B_GA + B_GC + B_TV);
        sage_body<ISF32>(p.x_o, p.ei_log, p.ei_log + EL, p.cnt_o,
                         p.part_lg + r8 * 8, EL, rb, B_LG, red);
    } else if (b < B_GA + B_GC + B_TV + B_LG + B_MN) {
        const int rb = b - (B_GA + B_GC + B_TV + B_LG);
        if (rb < 8) mean_body<3, ISF32>(p.x_m, p.part_mn_m + r8 * 4, NM, rb, 8, red);
        else        mean_body<4, ISF32>(p.x_o, p.part_mn_o + r8 * 4, NO, rb - 8, 40, red);
    } else {
        warm_body(p, b - (B_GA + B_GC + B_TV + B_LG + B_MN), ISF32, red);
    }
}

__global__ __launch_bounds__(256, 8) void k1_kernel(const Par p) {
    __shared__ __align__(16) uint4 stage[512];   // 8 KB: double-buffered 256 edges
    __shared__ float red[288];
    if (*p.flag) k1_body<true >(p, stage, red);
    else         k1_body<false>(p, stage, red);
}

// ---- final: 2 blocks. block 0 -> g_m, block 1 -> g_o ----
template<bool ISF32>
__device__ __forceinline__ void final_body(const Par p) {
    __shared__ float vA[H], vB[H], vC[H], vD[H];
    __shared__ float matp[256];
    __shared__ float sc[12];
    const int t = threadIdx.x;

    if (blockIdx.x == 0) {
        // ---- g_m ----
        if (t < 5) {                       // tv scalars a0..a3, aw
            float s = 0.f;
#pragma unroll
            for (int r = 0; r < 8; ++r) s += p.part_tv[r * 8 + t];
            sc[t] = s;
        } else if (t >= 8 && t < 11) {     // machine mean sums
            const int k = t - 8;
            float s = 0.f;
#pragma unroll
            for (int r = 0; r < 8; ++r) s += p.part_mn_m[r * 4 + k];
            sc[5 + k] = s;
        }
        __syncthreads();
        if (t < H) {
            float tv = sc[4] * ldf<ISF32>(p.bo, t);
#pragma unroll
            for (int k = 0; k < 4; ++k)
                tv = fmaf(sc[k], ldf<ISF32>(p.Wo, k * H + t), tv);
            vA[t] = tv * (1.f / NM);       // vtv
            float mhm = ldf<ISF32>(p.bm, t);
#pragma unroll
            for (int k = 0; k < 3; ++k)
                mhm = fmaf(sc[5 + k] * (1.f / NM), ldf<ISF32>(p.Wm, k * H + t), mhm);
            vB[t] = mhm;                   // vmhm
        }
        __syncthreads();
        {
            const int half = t >> 7, tt = t & 127;
            float acc = (half == 0) ? ldf<ISF32>(p.bl_tv, tt) : 0.f;
            const int k0 = half * 64;
#pragma unroll 8
            for (int k = k0; k < k0 + 64; ++k) {
                acc = fmaf(vA[k], ldf<ISF32>(p.Wl_tv, k * H + tt), acc);
                acc = fmaf(vB[k], ldf<ISF32>(p.Wr_tv, k * H + tt), acc);
            }
            matp[t] = acc;
        }
        __syncthreads();
        if (t < H) {
            const float r = matp[t] + matp[t + 128];
            if constexpr (ISF32) ((float*)p.out)[t] = r;
            else                 ((bf16*)p.out)[t] = __float2bfloat16(r);
        }
    } else {
        // ---- g_o ----
        {   // fold replicated channel accumulators
            const int col = t & 127;
            const float* srcp = (t < 128) ? (p.part_a + col) : (p.part_c + col);
            float s = 0.f;
#pragma unroll 8
            for (int r = 0; r < 16; ++r) s += srcp[r * H];
            if (t < 128) vA[col] = s; else vB[col] = s;
        }
        if (t < 5) {                       // log scalars
            float s = 0.f;
#pragma unroll
            for (int r = 0; r < 8; ++r) s += p.part_lg[r * 8 + t];
            sc[t] = s;
        } else if (t >= 8 && t < 12) {     // op mean sums
            const int k = t - 8;
            float s = 0.f;
#pragma unroll
            for (int r = 0; r < 8; ++r) s += p.part_mn_o[r * 4 + k];
            sc[5 + k] = s;
        }
        __syncthreads();
        if (t < H) {
            float mho = ldf<ISF32>(p.bo, t);
#pragma unroll
            for (int k = 0; k < 4; ++k)
                mho = fmaf(sc[5 + k] * (1.f / NO), ldf<ISF32>(p.Wo, k * H + t), mho);
            float lg = sc[4] * ldf<ISF32>(p.bo, t);
#pragma unroll
            for (int k = 0; k < 4; ++k)
                lg = fmaf(sc[k], ldf<ISF32>(p.Wo, k * H + t), lg);
            vD[t] = mho;                   // vmho
            vC[t] = lg * (1.f / NO);       // vlog
            vA[t] = vA[t] * (1.f / NO) + mho;   // GINE-a vector
            vB[t] = vB[t] * (1.f / NO) + mho;   // GINE-c vector
        }
        __syncthreads();
        {
            const int half = t >> 7, tt = t & 127;
            float acc = (half == 0)
                ? ldf<ISF32>(p.bn_a, tt) + ldf<ISF32>(p.bn_c, tt) + ldf<ISF32>(p.bl_log, tt)
                : 0.f;
            const int k0 = half * 64;
#pragma unroll 8
            for (int k = k0; k < k0 + 64; ++k) {
                acc = fmaf(vA[k], ldf<ISF32>(p.Wn_a, k * H + tt), acc);
                acc = fmaf(vB[k], ldf<ISF32>(p.Wn_c, k * H + tt), acc);
                acc = fmaf(vC[k], ldf<ISF32>(p.Wl_log, k * H + tt), acc);
                acc = fmaf(vD[k], ldf<ISF32>(p.Wr_log, k * H + tt), acc);
            }
            matp[t] = acc;
        }
        __syncthreads();
        if (t < H) {
            const float r = (matp[t] + matp[t + 128]) * (1.f / 3.f);
            if constexpr (ISF32) ((float*)p.out)[H + t] = r;
            else                 ((bf16*)p.out)[H + t] = __float2bfloat16(r);
        }
    }
}

__global__ __launch_bounds__(256) void final_kernel(const Par p) {
    if (*p.flag) final_body<true >(p);
    else         final_body<false>(p);
}

extern "C" void kernel_launch(void* const* d_in, const int* in_sizes, int n_in,
                              void* d_out, int out_size, void* d_ws, size_t ws_size,
                              hipStream_t stream) {
    char* ws = (char*)d_ws;
    Par p;
    p.x_m   = d_in[0];  p.x_o   = d_in[1];
    p.ea_a  = d_in[2];  p.ea_c  = d_in[3];
    p.ei_a  = (const int*)d_in[4];
    p.ei_c  = (const int*)d_in[5];
    p.ei_tv = (const int*)d_in[6];
    p.ei_log= (const int*)d_in[7];
    p.Wm = d_in[8];  p.bm = d_in[9];  p.Wo = d_in[10]; p.bo = d_in[11];
    p.Wn_a = d_in[12]; p.bn_a = d_in[13]; p.We_a = d_in[14]; p.be_a = d_in[15];
    p.Wn_c = d_in[16]; p.bn_c = d_in[17]; p.We_c = d_in[18]; p.be_c = d_in[19];
    p.Wl_tv = d_in[20]; p.bl_tv = d_in[21]; p.Wr_tv = d_in[22];
    p.Wl_log = d_in[23]; p.bl_log = d_in[24]; p.Wr_log = d_in[25];

    // Workspace layout (bytes):
    //   [0,       20480)   cnt_m      int[5000] (padded)      } zero range A
    //   [20480,  430080)   cnt_o      int[102400]             }
    //   [430080, 430084)   flag       (written by zero_kernel detect block)
    //   [430592, 438784)   part_a     float[16][128]          } zero range B
    //   [438784, 446976)   part_c     float[16][128]          }
    //   [446976, 447232)   part_tv    float[8][8]             }
    //   [447232, 447488)   part_lg    float[8][8]             }
    //   [447488, 447616)   part_mn_m  float[8][4]             }
    //   [447616, 447744)   part_mn_o  float[8][4]             }
    //   [447744, 447776)   sink                               }
    p.wsbase    = ws;
    p.cnt_m     = (int*)(ws);
    p.cnt_o     = (int*)(ws + 20480);
    p.flagw     = (int*)(ws + 430080);
    p.flag      = p.flagw;
    p.part_a    = (float*)(ws + 430592);
    p.part_c    = (float*)(ws + 438784);
    p.part_tv   = (float*)(ws + 446976);
    p.part_lg   = (float*)(ws + 447232);
    p.part_mn_m = (float*)(ws + 447488);
    p.part_mn_o = (float*)(ws + 447616);
    p.sink      = (float*)(ws + 447744);
    p.out  = d_out;

    zero_kernel<<<Z_BLOCKS, 256, 0, stream>>>(p);       // zero ws + dtype flag
    count_kernel<<<K0_BLOCKS, 256, 0, stream>>>(p);     // counts, wide (quarantined)
    k1_kernel<<<K1_BLOCKS, 256, 0, stream>>>(p);        // gine + sage + means + warm
    final_kernel<<<2, 256, 0, stream>>>(p);             // mat-vecs + output
}

// Round 8
// 197.239 us; speedup vs baseline: 1.0334x; 1.0334x over previous
//
#include <hip/hip_runtime.h>
#include <hip/hip_bf16.h>
#include <stdint.h>

// Problem constants (from reference)
#define H   128
#define NM  5000
#define NO  100000
#define EA  1000000
#define EC  500000
#define ET  1000000
#define EL  500000

typedef __hip_bfloat16 bf16;
typedef float f32x4 __attribute__((ext_vector_type(4)));
typedef short short8 __attribute__((ext_vector_type(8)));

// R8 = R6 structure (best, 193.9) + software-pipelined gine staging.
//   Z  : zero workspace + dtype flag
//   K1 : count_m | count_o | gine_a | gine_c | means | warm   (counts hidden)
//   K2 : sage_tv | sage_log   (reads counts across kernel boundary)
//   K3 : final
// R7 lesson: quarantined counts cost ~22us serial vs +8.5us hidden in K1.
#define CM_BLK 64
#define CO_BLK 192
#define CNT_BLOCKS (CM_BLK + CO_BLK)                    // 256
#define B_GA 1024
#define B_GC 512
#define B_MN 48
#define B_WM 6
#define K1_BLOCKS (CNT_BLOCKS + B_GA + B_GC + B_MN + B_WM)   // 1846 <= 2048 slots
#define B_TV 512
#define B_LG 256
#define K2_BLOCKS (B_TV + B_LG)

// zero kernel geometry: range A=[0,430080) cnt arrays, B=[430592,447776) parts.
#define ZA_U4 26880
#define ZB_OFF 430592
#define ZB_U4 1074
#define Z_BLOCKS 66

struct Par {
    const void *x_m, *x_o, *ea_a, *ea_c;
    const int *ei_a, *ei_c, *ei_tv, *ei_log;
    const void *Wm, *bm, *Wo, *bo;
    const void *Wn_a, *bn_a, *We_a, *be_a;
    const void *Wn_c, *bn_c, *We_c, *be_c;
    const void *Wl_tv, *bl_tv, *Wr_tv, *Wl_log, *bl_log, *Wr_log;
    int *cnt_m, *cnt_o;
    float *part_a, *part_c;        // [16][128] replicated accumulators
    float *part_tv, *part_lg;      // [8][8]
    float *part_mn_m, *part_mn_o;  // [8][4]
    float *sink;
    char *wsbase;
    int *flagw;
    const int *flag;
    void *out;
};

// ---- dtype-flexible loads ----
template<bool ISF32>
__device__ __forceinline__ float ldf(const void* p, int i) {
    if constexpr (ISF32) return ((const float*)p)[i];
    else                 return __bfloat162float(((const bf16*)p)[i]);
}

__device__ __forceinline__ float bflo(uint32_t v) {
    union { uint32_t u; float f; } c; c.u = v << 16; return c.f;
}
__device__ __forceinline__ float bfhi(uint32_t v) {
    union { uint32_t u; float f; } c; c.u = v & 0xFFFF0000u; return c.f;
}

__device__ __forceinline__ uint32_t pack2(float a, float b) {
    union { bf16 h; uint16_t u; } ca, cb;
    ca.h = __float2bfloat16(a); cb.h = __float2bfloat16(b);
    return (uint32_t)ca.u | ((uint32_t)cb.u << 16);
}

__device__ __forceinline__ uint16_t bfbits(float a) {
    union { bf16 h; uint16_t u; } c; c.h = __float2bfloat16(a); return c.u;
}

template<bool ISF32>
__device__ __forceinline__ float4 ld4(const void* p, int row) {
    if constexpr (ISF32) return ((const float4*)p)[row];
    else {
        const uint2 t = ((const uint2*)p)[row];
        float4 r; r.x = bflo(t.x); r.y = bfhi(t.x); r.z = bflo(t.y); r.w = bfhi(t.y);
        return r;
    }
}

__device__ __forceinline__ float wred(float v) {
#pragma unroll
    for (int o = 32; o; o >>= 1) v += __shfl_down(v, o, 64);
    return v;
}

// ---- Z: zero workspace + dtype-detect flag ----
__global__ __launch_bounds__(256) void zero_kernel(const Par p) {
    const int t = threadIdx.x;
    const int b = blockIdx.x;
    const uint4 z = (uint4){0, 0, 0, 0};
    if (b < 64) {
        uint4* a = (uint4*)p.wsbase;
        for (int i = b * 256 + t; i < ZA_U4; i += 64 * 256) a[i] = z;
    } else if (b == 64) {
        uint4* bp = (uint4*)(p.wsbase + ZB_OFF);
        for (int i = t; i < ZB_U4; i += 256) bp[i] = z;
    } else {
        // dtype detect: f32 inputs show 0xFF exponent-field patterns in the
        // mantissa-low u16 halves; bf16 N(0,1) never does.
        __shared__ int fl;
        if (t == 0) fl = 0;
        __syncthreads();
        int local = 0;
        const uint16_t* xm = (const uint16_t*)p.x_m;
        for (int i = t; i < 15000; i += 256)
            if (((xm[i] >> 7) & 0xFF) == 0xFF) local = 1;
        if (local) atomicOr(&fl, 1);
        __syncthreads();
        if (t == 0) *p.flagw = fl;
    }
}

// ---- cnt_m: LDS-private histogram, 2x16-bit counters packed per word so the
// hist costs 10 KB (keeps K1 at 8 blocks/CU). Max count/bin = 15625 < 2^16.
// Rotated flush start so concurrent blocks hit disjoint address ranges.
__device__ __forceinline__ void cntm_body(const Par p, int rb, uint32_t* hist /*2500*/) {
    const int t = threadIdx.x;
    for (int i = t; i < 2500; i += 256) hist[i] = 0;
    __syncthreads();
    const int2* dst2 = (const int2*)(p.ei_tv + ET);
    for (int i = rb * 256 + t; i < ET / 2; i += CM_BLK * 256) {
        const int2 d = dst2[i];
        atomicAdd(&hist[d.x >> 1], 1u << ((d.x & 1) * 16));
        atomicAdd(&hist[d.y >> 1], 1u << ((d.y & 1) * 16));
    }
    __syncthreads();
    const int rot = (rb * 157) % 2500;
    for (int i = t; i < 2500; i += 256) {
        int j = i + rot; if (j >= 2500) j -= 2500;
        const uint32_t v = hist[j];
        const int lo = (int)(v & 0xFFFFu), hi = (int)(v >> 16);
        if (lo) atomicAdd(&p.cnt_m[2 * j], lo);
        if (hi) atomicAdd(&p.cnt_m[2 * j + 1], hi);
    }
}

// ---- cnt_o: 500K direct global atomics over 102400 bins (~5/addr) ----
__device__ __forceinline__ void cnto_body(const Par p, int rb) {
    const int t = threadIdx.x;
    const int4* d4 = (const int4*)(p.ei_log + EL);
    for (int i = rb * 256 + t; i < EL / 4; i += CO_BLK * 256) {
        const int4 d = d4[i];
        atomicAdd(&p.cnt_o[d.x], 1);
        atomicAdd(&p.cnt_o[d.y], 1);
        atomicAdd(&p.cnt_o[d.z], 1);
        atomicAdd(&p.cnt_o[d.w], 1);
    }
}

// ---- gather prefetch state: load() issues the raw loads into registers;
// pack() (bit-ops / cvts) is deferred until after the MFMA phase, so the
// gather latency of granule g+1 hides under granule g's MFMAs (T14 split).
template<int FIN, int ED, bool ISF32>
struct Pref {
    bool act;
    uint32_t u0, u1, u2, u3, u4, u5;
    float f0, f1, f2, f3, f4, f5;
    __device__ __forceinline__ void load(const int* __restrict__ src,
                                         const void* __restrict__ ea,
                                         const void* __restrict__ x,
                                         int base, int ecnt, int tid) {
        act = tid < ecnt;
        if (!act) return;
        const int ej = base + tid;
        const int s = src[ej];
        if constexpr (!ISF32) {
            const uint16_t* xb = (const uint16_t*)x;
            const uint16_t* eb = (const uint16_t*)ea;
            if constexpr (FIN == 4) {              // gine_c: x row = uint2
                const uint2 xr = ((const uint2*)x)[s];
                u0 = xr.x; u1 = xr.y;
                u2 = eb[ej];                        // ED == 1
            } else {                                // gine_a: FIN=3, ED=3
                u0 = xb[s * 3]; u1 = xb[s * 3 + 1]; u2 = xb[s * 3 + 2];
                u3 = eb[ej * 3]; u4 = eb[ej * 3 + 1]; u5 = eb[ej * 3 + 2];
            }
        } else {
            if constexpr (FIN == 4) {
                const float4 xv = ((const float4*)x)[s];
                f0 = xv.x; f1 = xv.y; f2 = xv.z; f3 = xv.w;
                f4 = ((const float*)ea)[ej];        // ED == 1
            } else {
                const float* xf = (const float*)x;
                f0 = xf[s * 3]; f1 = xf[s * 3 + 1]; f2 = xf[s * 3 + 2];
                const float* ef = (const float*)ea;
                f3 = ef[ej * 3]; f4 = ef[ej * 3 + 1]; f5 = ef[ej * 3 + 2];
            }
        }
    }
    __device__ __forceinline__ uint4 pack() const {
        uint4 pk = (uint4){0, 0, 0, 0};
        if (!act) return pk;                        // zero rows contribute 0
        if constexpr (!ISF32) {
            if constexpr (FIN == 4) {               // KT=5: f4=ea, f5=1.0
                pk.x = u0; pk.y = u1;
                pk.z = u2 | (0x3F80u << 16);
            } else {                                 // KT=6: f6=1.0
                pk.x = u0 | (u1 << 16);
                pk.y = u2 | (u3 << 16);
                pk.z = u4 | (u5 << 16);
                pk.w = 0x00003F80u;
            }
        } else {
            if constexpr (FIN == 4) {
                pk.x = pack2(f0, f1); pk.y = pack2(f2, f3);
                pk.z = pack2(f4, 1.0f);
            } else {
                pk.x = pack2(f0, f1); pk.y = pack2(f2, f3);
                pk.z = pack2(f4, f5); pk.w = pack2(1.0f, 0.f);
            }
        }
        return pk;
    }
};

// ---- GINE via MFMA, occupancy-safe (channels split across waves) ----
// Granule = 256 edges staged once per block (bf16, double-buffered LDS).
// F[256][8]: features + edge-attrs + constant-1 column (bias = W-row KT).
// Wave w owns channels [32w, 32w+32). Per-block channel sums atomicAdd'ed
// into a replicated 128-vector. Staging is software-pipelined: loads for
// granule g+1 issue right after the barrier, pack happens next iteration.
template<int FIN, int ED, bool ISF32>
__device__ __forceinline__ void gine_body(
    const int* __restrict__ src, const void* __restrict__ ea,
    const void* __restrict__ x, const void* __restrict__ We,
    const void* __restrict__ be, const void* __restrict__ Wx,
    const void* __restrict__ bx, float* __restrict__ partv,
    int E, int relb, int nblk, uint4* stage /* [2][256] */)
{
    constexpr int KT = FIN + ED;          // bias row at k=KT; KT+1 <= 8
    const int tid = threadIdx.x;
    const int lane = tid & 63;
    const int wv = tid >> 6;
    const int q = lane >> 4;
    const int col = lane & 15;

    // B fragments for this wave's 2 N-tiles; only quad 0 holds nonzeros (K<=7).
    short8 bfr[2];
#pragma unroll
    for (int nt = 0; nt < 2; ++nt) {
        const int ch = wv * 32 + nt * 16 + col;
        short8 s = (short8)0;
#pragma unroll
        for (int j = 0; j < 8; ++j) {
            const int k = q * 8 + j;
            float w = 0.f;
            if (k < FIN)       w = ldf<ISF32>(Wx, k * H + ch);
            else if (k < KT)   w = ldf<ISF32>(We, (k - FIN) * H + ch);
            else if (k == KT)  w = ldf<ISF32>(bx, ch) + ldf<ISF32>(be, ch);
            s[j] = (short)bfbits(w);
        }
        bfr[nt] = s;
    }
    f32x4 acc0 = (f32x4)0.f, acc1 = (f32x4)0.f;
    const f32x4 zero4 = (f32x4)0.f;

    const int G = (E + 255) >> 8;
    const int chunk = (G + nblk - 1) / nblk;
    const int g0 = relb * chunk;
    const int g1 = min(g0 + chunk, G);

    Pref<FIN, ED, ISF32> cur, nxt;
    if (g0 < g1) {
        const int b0 = g0 << 8;
        cur.load(src, ea, x, b0, min(256, E - b0), tid);
    }
    for (int g = g0; g < g1; ++g) {
        const int buf = g & 1;
        stage[buf * 256 + tid] = cur.pack();   // cur's loads landed long ago
        __syncthreads();                       // stage visible; guards buf reuse
        nxt.act = false;
        if (g + 1 < g1) {                      // issue next gather NOW --
            const int nb = (g + 1) << 8;       // latency hides under MFMAs
            nxt.load(src, ea, x, nb, min(256, E - nb), tid);
        }
        const uint4* st = stage + buf * 256;
#pragma unroll 4
        for (int mt = 0; mt < 16; ++mt) {
            union { short8 s; uint4 u; } au;
            au.u = (uint4){0, 0, 0, 0};
            if (lane < 16) au.u = st[mt * 16 + lane];   // exec-masked A-frag
            f32x4 d0 = __builtin_amdgcn_mfma_f32_16x16x32_bf16(au.s, bfr[0], zero4, 0, 0, 0);
            f32x4 d1 = __builtin_amdgcn_mfma_f32_16x16x32_bf16(au.s, bfr[1], zero4, 0, 0, 0);
            acc0 += __builtin_elementwise_max(d0, zero4);
            acc1 += __builtin_elementwise_max(d1, zero4);
        }
        cur = nxt;
    }
    // fold: 4 regs (edge rows) + cross-quad -> channel sums on lanes 0..15
    float v0 = acc0[0] + acc0[1] + acc0[2] + acc0[3];
    v0 += __shfl_xor(v0, 16, 64);
    v0 += __shfl_xor(v0, 32, 64);
    float v1 = acc1[0] + acc1[1] + acc1[2] + acc1[3];
    v1 += __shfl_xor(v1, 16, 64);
    v1 += __shfl_xor(v1, 32, 64);
    if (lane < 16) {
        atomicAdd(&partv[wv * 32 + col], v0);
        atomicAdd(&partv[wv * 32 + 16 + col], v1);
    }
}

// ---- component sums of x over nodes ----
template<int FIN, bool ISF32>
__device__ __forceinline__ void mean_body(
    const void* __restrict__ x, float* __restrict__ partv, int N,
    int relb, int nblk, float* lds)
{
    const int stride = nblk * 256;
    float acc[FIN];
#pragma unroll
    for (int k = 0; k < FIN; ++k) acc[k] = 0.f;
    for (int n = relb * 256 + threadIdx.x; n < N; n += stride) {
        if constexpr (FIN == 4) {
            const float4 xv = ld4<ISF32>(x, n);
            acc[0] += xv.x; acc[1] += xv.y; acc[2] += xv.z; acc[3] += xv.w;
        } else {
#pragma unroll
            for (int k = 0; k < FIN; ++k) acc[k] += ldf<ISF32>(x, n * FIN + k);
        }
    }
#pragma unroll
    for (int k = 0; k < FIN; ++k) acc[k] = wred(acc[k]);
    if ((threadIdx.x & 63) == 0) {
        const int w = threadIdx.x >> 6;
#pragma unroll
        for (int k = 0; k < 4; ++k) lds[w * 4 + k] = (k < FIN) ? acc[k] : 0.f;
    }
    __syncthreads();
    if (threadIdx.x < 4)
        atomicAdd(&partv[threadIdx.x],
                  lds[threadIdx.x] + lds[4 + threadIdx.x]
                + lds[8 + threadIdx.x] + lds[12 + threadIdx.x]);
}

// ---- SAGE edge reduction, int4-batched ----
template<bool ISF32>
__device__ __forceinline__ void sage_body(
    const void* __restrict__ x, const int* __restrict__ src,
    const int* __restrict__ dst, const int* __restrict__ cnt,
    float* __restrict__ partv, int E, int relb, int nblk, float* lds)
{
    const int tid = threadIdx.x;
    const int nv = E >> 2;
    const int stride = nblk * 256;
    float a0 = 0.f, a1 = 0.f, a2 = 0.f, a3 = 0.f, aw = 0.f;
#pragma unroll 2
    for (int i = relb * 256 + tid; i < nv; i += stride) {
        const int4 s4 = ((const int4*)src)[i];
        const int4 d4 = ((const int4*)dst)[i];
        const int c0 = cnt[d4.x], c1 = cnt[d4.y], c2 = cnt[d4.z], c3 = cnt[d4.w];
        const float4 x0 = ld4<ISF32>(x, s4.x);
        const float4 x1 = ld4<ISF32>(x, s4.y);
        const float4 x2 = ld4<ISF32>(x, s4.z);
        const float4 x3 = ld4<ISF32>(x, s4.w);
        const float i0 = __builtin_amdgcn_rcpf((float)(c0 > 0 ? c0 : 1));
        const float i1 = __builtin_amdgcn_rcpf((float)(c1 > 0 ? c1 : 1));
        const float i2 = __builtin_amdgcn_rcpf((float)(c2 > 0 ? c2 : 1));
        const float i3 = __builtin_amdgcn_rcpf((float)(c3 > 0 ? c3 : 1));
        a0 = fmaf(i0, x0.x, a0); a1 = fmaf(i0, x0.y, a1); a2 = fmaf(i0, x0.z, a2); a3 = fmaf(i0, x0.w, a3); aw += i0;
        a0 = fmaf(i1, x1.x, a0); a1 = fmaf(i1, x1.y, a1); a2 = fmaf(i1, x1.z, a2); a3 = fmaf(i1, x1.w, a3); aw += i1;
        a0 = fmaf(i2, x2.x, a0); a1 = fmaf(i2, x2.y, a1); a2 = fmaf(i2, x2.z, a2); a3 = fmaf(i2, x2.w, a3); aw += i2;
        a0 = fmaf(i3, x3.x, a0); a1 = fmaf(i3, x3.y, a1); a2 = fmaf(i3, x3.z, a2); a3 = fmaf(i3, x3.w, a3); aw += i3;
    }
    a0 = wred(a0); a1 = wred(a1); a2 = wred(a2); a3 = wred(a3); aw = wred(aw);
    if ((tid & 63) == 0) {
        float* w5 = lds + (tid >> 6) * 5;
        w5[0] = a0; w5[1] = a1; w5[2] = a2; w5[3] = a3; w5[4] = aw;
    }
    __syncthreads();
    if (tid < 5)
        atomicAdd(&partv[tid], lds[tid] + lds[5 + tid] + lds[10 + tid] + lds[15 + tid]);
}

// ---- warm: stream final-kernel weights into L2/L3 ----
__device__ __forceinline__ void warm_body(const Par p, int rb, bool f32, float* lds) {
    const void* w[6] = {p.Wn_a, p.Wn_c, p.Wl_tv, p.Wr_tv, p.Wl_log, p.Wr_log};
    const uint4* u = (const uint4*)w[rb];
    const int n16 = (f32 ? (H * H * 4) : (H * H * 2)) / 16;
    uint32_t s = 0;
    for (int i = threadIdx.x; i < n16; i += 256) {
        const uint4 v = u[i];
        s ^= v.x ^ v.y ^ v.z ^ v.w;
    }
    lds[threadIdx.x] = (float)(s & 1);
    __syncthreads();
    if (threadIdx.x == 0) {
        float acc = 0.f;
        for (int i = 0; i < 256; ++i) acc += lds[i];
        p.sink[rb] = acc;   // dummy sink, never read
    }
}

// ---- K1 compute roles (after the count blocks): gine_a | gine_c | means | warm ----
template<bool ISF32>
__device__ __forceinline__ void k1_body(const Par p, uint4* stage, float* red, int b) {
    if (b < B_GA) {
        gine_body<3, 3, ISF32>(p.ei_a, p.ea_a, p.x_m, p.We_a, p.be_a, p.Wm, p.bm,
                               p.part_a + (b & 15) * H, EA, b, B_GA, stage);
    } else if (b < B_GA + B_GC) {
        const int rb = b - B_GA;
        gine_body<4, 1, ISF32>(p.ei_c, p.ea_c, p.x_o, p.We_c, p.be_c, p.Wo, p.bo,
                               p.part_c + (rb & 15) * H, EC, rb, B_GC, stage);
    } else if (b < B_GA + B_GC + B_MN) {
        const int rb = b - (B_GA + B_GC);
        if (rb < 8) mean_body<3, ISF32>(p.x_m, p.part_mn_m + (rb & 7) * 4, NM, rb, 8, red);
        else        mean_body<4, ISF32>(p.x_o, p.part_mn_o + ((rb - 8) & 7) * 4, NO, rb - 8, 40, red);
    } else {
        warm_body(p, b - (B_GA + B_GC + B_MN), ISF32, red);
    }
}

// LDS budget: stage 8192 + red 1152 + hist 10000 = 19344 B <= 20480 (8 blocks/CU).
__global__ __launch_bounds__(256, 8) void k1_kernel(const Par p) {
    __shared__ __align__(16) uint4 stage[512];   // 8 KB: double-buffered 256 edges
    __shared__ float red[288];
    __shared__ uint32_t hist[2500];              // 10 KB packed cnt_m histogram
    const int b = blockIdx.x;
    if (b < CM_BLK)          { cntm_body(p, b, hist); return; }
    if (b < CNT_BLOCKS)      { cnto_body(p, b - CM_BLK); return; }
    const int cb = b - CNT_BLOCKS;
    if (*p.flag) k1_body<true >(p, stage, red, cb);
    else         k1_body<false>(p, stage, red, cb);
}

// ---- K2: sage (needs counts; kernel boundary = coherence) ----
__global__ __launch_bounds__(256, 8) void k2_kernel(const Par p) {
    __shared__ float red[288];
    const int b = blockIdx.x;
    const bool f32 = (*p.flag != 0);
    if (b < B_TV) {
        if (f32) sage_body<true >(p.x_o, p.ei_tv, p.ei_tv + ET, p.cnt_m,
                                  p.part_tv + (b & 7) * 8, ET, b, B_TV, red);
        else     sage_body<false>(p.x_o, p.ei_tv, p.ei_tv + ET, p.cnt_m,
                                  p.part_tv + (b & 7) * 8, ET, b, B_TV, red);
    } else {
        const int rb = b - B_TV;
        if (f32) sage_body<true >(p.x_o, p.ei_log, p.ei_log + EL, p.cnt_o,
                                  p.part_lg + (rb & 7) * 8, EL, rb, B_LG, red);
        else     sage_body<false>(p.x_o, p.ei_log, p.ei_log + EL, p.cnt_o,
                                  p.part_lg + (rb & 7) * 8, EL, rb, B_LG, red);
    }
}

// ---- final: 2 blocks. block 0 -> g_m, block 1 -> g_o ----
template<bool ISF32>
__device__ __forceinline__ void final_body(const Par p) {
    __shared__ float vA[H], vB[H], vC[H], vD[H];
    __shared__ float matp[256];
    __shared__ float sc[12];
    const int t = threadIdx.x;

    if (blockIdx.x == 0) {
        // ---- g_m ----
        if (t < 5) {                       // tv scalars a0..a3, aw
            float s = 0.f;
#pragma unroll
            for (int r = 0; r < 8; ++r) s += p.part_tv[r * 8 + t];
            sc[t] = s;
        } else if (t >= 8 && t < 11) {     // machine mean sums
            const int k = t - 8;
            float s = 0.f;
#pragma unroll
            for (int r = 0; r < 8; ++r) s += p.part_mn_m[r * 4 + k];
            sc[5 + k] = s;
        }
        __syncthreads();
        if (t < H) {
            float tv = sc[4] * ldf<ISF32>(p.bo, t);
#pragma unroll
            for (int k = 0; k < 4; ++k)
                tv = fmaf(sc[k], ldf<ISF32>(p.Wo, k * H + t), tv);
            vA[t] = tv * (1.f / NM);       // vtv
            float mhm = ldf<ISF32>(p.bm, t);
#pragma unroll
            for (int k = 0; k < 3; ++k)
                mhm = fmaf(sc[5 + k] * (1.f / NM), ldf<ISF32>(p.Wm, k * H + t), mhm);
            vB[t] = mhm;                   // vmhm
        }
        __syncthreads();
        {
            const int half = t >> 7, tt = t & 127;
            float acc = (half == 0) ? ldf<ISF32>(p.bl_tv, tt) : 0.f;
            const int k0 = half * 64;
#pragma unroll 8
            for (int k = k0; k < k0 + 64; ++k) {
                acc = fmaf(vA[k], ldf<ISF32>(p.Wl_tv, k * H + tt), acc);
                acc = fmaf(vB[k], ldf<ISF32>(p.Wr_tv, k * H + tt), acc);
            }
            matp[t] = acc;
        }
        __syncthreads();
        if (t < H) {
            const float r = matp[t] + matp[t + 128];
            if constexpr (ISF32) ((float*)p.out)[t] = r;
            else                 ((bf16*)p.out)[t] = __float2bfloat16(r);
        }
    } else {
        // ---- g_o ----
        {   // fold replicated channel accumulators
            const int col = t & 127;
            const float* srcp = (t < 128) ? (p.part_a + col) : (p.part_c + col);
            float s = 0.f;
#pragma unroll 8
            for (int r = 0; r < 16; ++r) s += srcp[r * H];
            if (t < 128) vA[col] = s; else vB[col] = s;
        }
        if (t < 5) {                       // log scalars
            float s = 0.f;
#pragma unroll
            for (int r = 0; r < 8; ++r) s += p.part_lg[r * 8 + t];
            sc[t] = s;
        } else if (t >= 8 && t < 12) {     // op mean sums
            const int k = t - 8;
            float s = 0.f;
#pragma unroll
            for (int r = 0; r < 8; ++r) s += p.part_mn_o[r * 4 + k];
            sc[5 + k] = s;
        }
        __syncthreads();
        if (t < H) {
            float mho = ldf<ISF32>(p.bo, t);
#pragma unroll
            for (int k = 0; k < 4; ++k)
                mho = fmaf(sc[5 + k] * (1.f / NO), ldf<ISF32>(p.Wo, k * H + t), mho);
            float lg = sc[4] * ldf<ISF32>(p.bo, t);
#pragma unroll
            for (int k = 0; k < 4; ++k)
                lg = fmaf(sc[k], ldf<ISF32>(p.Wo, k * H + t), lg);
            vD[t] = mho;                   // vmho
            vC[t] = lg * (1.f / NO);       // vlog
            vA[t] = vA[t] * (1.f / NO) + mho;   // GINE-a vector
            vB[t] = vB[t] * (1.f / NO) + mho;   // GINE-c vector
        }
        __syncthreads();
        {
            const int half = t >> 7, tt = t & 127;
            float acc = (half == 0)
                ? ldf<ISF32>(p.bn_a, tt) + ldf<ISF32>(p.bn_c, tt) + ldf<ISF32>(p.bl_log, tt)
                : 0.f;
            const int k0 = half * 64;
#pragma unroll 8
            for (int k = k0; k < k0 + 64; ++k) {
                acc = fmaf(vA[k], ldf<ISF32>(p.Wn_a, k * H + tt), acc);
                acc = fmaf(vB[k], ldf<ISF32>(p.Wn_c, k * H + tt), acc);
                acc = fmaf(vC[k], ldf<ISF32>(p.Wl_log, k * H + tt), acc);
                acc = fmaf(vD[k], ldf<ISF32>(p.Wr_log, k * H + tt), acc);
            }
            matp[t] = acc;
        }
        __syncthreads();
        if (t < H) {
            const float r = (matp[t] + matp[t + 128]) * (1.f / 3.f);
            if constexpr (ISF32) ((float*)p.out)[H + t] = r;
            else                 ((bf16*)p.out)[H + t] = __float2bfloat16(r);
        }
    }
}

__global__ __launch_bounds__(256) void final_kernel(const Par p) {
    if (*p.flag) final_body<true >(p);
    else         final_body<false>(p);
}

extern "C" void kernel_launch(void* const* d_in, const int* in_sizes, int n_in,
                              void* d_out, int out_size, void* d_ws, size_t ws_size,
                              hipStream_t stream) {
    char* ws = (char*)d_ws;
    Par p;
    p.x_m   = d_in[0];  p.x_o   = d_in[1];
    p.ea_a  = d_in[2];  p.ea_c  = d_in[3];
    p.ei_a  = (const int*)d_in[4];
    p.ei_c  = (const int*)d_in[5];
    p.ei_tv = (const int*)d_in[6];
    p.ei_log= (const int*)d_in[7];
    p.Wm = d_in[8];  p.bm = d_in[9];  p.Wo = d_in[10]; p.bo = d_in[11];
    p.Wn_a = d_in[12]; p.bn_a = d_in[13]; p.We_a = d_in[14]; p.be_a = d_in[15];
    p.Wn_c = d_in[16]; p.bn_c = d_in[17]; p.We_c = d_in[18]; p.be_c = d_in[19];
    p.Wl_tv = d_in[20]; p.bl_tv = d_in[21]; p.Wr_tv = d_in[22];
    p.Wl_log = d_in[23]; p.bl_log = d_in[24]; p.Wr_log = d_in[25];

    // Workspace layout (bytes):
    //   [0,       20480)   cnt_m      int[5000] (padded)      } zero range A
    //   [20480,  430080)   cnt_o      int[102400]             }
    //   [430080, 430084)   flag       (written by zero_kernel detect block)
    //   [430592, 438784)   part_a     float[16][128]          } zero range B
    //   [438784, 446976)   part_c     float[16][128]          }
    //   [446976, 447232)   part_tv    float[8][8]             }
    //   [447232, 447488)   part_lg    float[8][8]             }
    //   [447488, 447616)   part_mn_m  float[8][4]             }
    //   [447616, 447744)   part_mn_o  float[8][4]             }
    //   [447744, 447776)   sink                               }
    p.wsbase    = ws;
    p.cnt_m     = (int*)(ws);
    p.cnt_o     = (int*)(ws + 20480);
    p.flagw     = (int*)(ws + 430080);
    p.flag      = p.flagw;
    p.part_a    = (float*)(ws + 430592);
    p.part_c    = (float*)(ws + 438784);
    p.part_tv   = (float*)(ws + 446976);
    p.part_lg   = (float*)(ws + 447232);
    p.part_mn_m = (float*)(ws + 447488);
    p.part_mn_o = (float*)(ws + 447616);
    p.sink      = (float*)(ws + 447744);
    p.out  = d_out;

    zero_kernel<<<Z_BLOCKS, 256, 0, stream>>>(p);     // zero ws + dtype flag
    k1_kernel<<<K1_BLOCKS, 256, 0, stream>>>(p);      // counts ∥ gine ∥ means ∥ warm
    k2_kernel<<<K2_BLOCKS, 256, 0, stream>>>(p);      // sage (reads counts)
    final_kernel<<<2, 256, 0, stream>>>(p);           // mat-vecs + output
}

// Round 9
// 184.263 us; speedup vs baseline: 1.1062x; 1.0704x over previous
//
#include <hip/hip_runtime.h>
#include <hip/hip_bf16.h>
#include <stdint.h>

// Problem constants (from reference)
#define H   128
#define NM  5000
#define NO  100000
#define EA  1000000
#define EC  500000
#define ET  1000000
#define EL  500000

typedef __hip_bfloat16 bf16;
typedef float f32x4 __attribute__((ext_vector_type(4)));
typedef short short8 __attribute__((ext_vector_type(8)));

// R9 = R6 structure (best, 193.9) + XCD-local cnt_o atomics.
//   Z  : zero workspace + dtype flag
//   K1 : count_m | count_o | gine_a | gine_c | means | warm   (counts hidden)
//   K2 : sage_tv | sage_log   (reads counts across kernel boundary)
//   K3 : final
// R8 lesson: gine gather prefetch = 0 effect; K1's +8.5us over the 42.8
// gine-floor is cnt_o's cross-XCD atomic line ping-pong (WRITE 0.78->19MB).
// Fix: partition cnt_o by dst-range x XCD (blockIdx%8 round-robins XCDs),
// so each cnt_o line only ever receives atomics from one XCD's L2.
#define CM_BLK 32
#define CO_BLK 192                  // 8 ranges x 24 chunks
#define CNT_BLOCKS (CM_BLK + CO_BLK)                    // 224 (mult of 8!)
#define B_GA 1024
#define B_GC 512
#define B_MN 48
#define B_WM 6
#define K1_BLOCKS (CNT_BLOCKS + B_GA + B_GC + B_MN + B_WM)   // 1814 <= 2048 slots
#define B_TV 512
#define B_LG 256
#define K2_BLOCKS (B_TV + B_LG)

// zero kernel geometry: range A=[0,430080) cnt arrays, B=[430592,447776) parts.
#define ZA_U4 26880
#define ZB_OFF 430592
#define ZB_U4 1074
#define Z_BLOCKS 66

struct Par {
    const void *x_m, *x_o, *ea_a, *ea_c;
    const int *ei_a, *ei_c, *ei_tv, *ei_log;
    const void *Wm, *bm, *Wo, *bo;
    const void *Wn_a, *bn_a, *We_a, *be_a;
    const void *Wn_c, *bn_c, *We_c, *be_c;
    const void *Wl_tv, *bl_tv, *Wr_tv, *Wl_log, *bl_log, *Wr_log;
    int *cnt_m, *cnt_o;
    float *part_a, *part_c;        // [16][128] replicated accumulators
    float *part_tv, *part_lg;      // [8][8]
    float *part_mn_m, *part_mn_o;  // [8][4]
    float *sink;
    char *wsbase;
    int *flagw;
    const int *flag;
    void *out;
};

// ---- dtype-flexible loads ----
template<bool ISF32>
__device__ __forceinline__ float ldf(const void* p, int i) {
    if constexpr (ISF32) return ((const float*)p)[i];
    else                 return __bfloat162float(((const bf16*)p)[i]);
}

__device__ __forceinline__ float bflo(uint32_t v) {
    union { uint32_t u; float f; } c; c.u = v << 16; return c.f;
}
__device__ __forceinline__ float bfhi(uint32_t v) {
    union { uint32_t u; float f; } c; c.u = v & 0xFFFF0000u; return c.f;
}

__device__ __forceinline__ uint32_t pack2(float a, float b) {
    union { bf16 h; uint16_t u; } ca, cb;
    ca.h = __float2bfloat16(a); cb.h = __float2bfloat16(b);
    return (uint32_t)ca.u | ((uint32_t)cb.u << 16);
}

__device__ __forceinline__ uint16_t bfbits(float a) {
    union { bf16 h; uint16_t u; } c; c.h = __float2bfloat16(a); return c.u;
}

template<bool ISF32>
__device__ __forceinline__ float4 ld4(const void* p, int row) {
    if constexpr (ISF32) return ((const float4*)p)[row];
    else {
        const uint2 t = ((const uint2*)p)[row];
        float4 r; r.x = bflo(t.x); r.y = bfhi(t.x); r.z = bflo(t.y); r.w = bfhi(t.y);
        return r;
    }
}

__device__ __forceinline__ float wred(float v) {
#pragma unroll
    for (int o = 32; o; o >>= 1) v += __shfl_down(v, o, 64);
    return v;
}

// ---- Z: zero workspace + dtype-detect flag ----
__global__ __launch_bounds__(256) void zero_kernel(const Par p) {
    const int t = threadIdx.x;
    const int b = blockIdx.x;
    const uint4 z = (uint4){0, 0, 0, 0};
    if (b < 64) {
        uint4* a = (uint4*)p.wsbase;
        for (int i = b * 256 + t; i < ZA_U4; i += 64 * 256) a[i] = z;
    } else if (b == 64) {
        uint4* bp = (uint4*)(p.wsbase + ZB_OFF);
        for (int i = t; i < ZB_U4; i += 256) bp[i] = z;
    } else {
        // dtype detect: f32 inputs show 0xFF exponent-field patterns in the
        // mantissa-low u16 halves; bf16 N(0,1) never does.
        __shared__ int fl;
        if (t == 0) fl = 0;
        __syncthreads();
        int local = 0;
        const uint16_t* xm = (const uint16_t*)p.x_m;
        for (int i = t; i < 15000; i += 256)
            if (((xm[i] >> 7) & 0xFF) == 0xFF) local = 1;
        if (local) atomicOr(&fl, 1);
        __syncthreads();
        if (t == 0) *p.flagw = fl;
    }
}

// ---- cnt_m: LDS-private histogram, 2x16-bit counters packed per word so the
// hist costs 10 KB (keeps K1 at 8 blocks/CU). Max count/bin = 31250 < 2^16.
// int4 scan; rotated flush so concurrent blocks hit disjoint address ranges.
// CM_BLK=32 (was 64): halves the global-flush atomic count; the longer scan
// (30 int4-iters) is streaming and hides under gine.
__device__ __forceinline__ void cntm_body(const Par p, int rb, uint32_t* hist /*2500*/) {
    const int t = threadIdx.x;
    for (int i = t; i < 2500; i += 256) hist[i] = 0;
    __syncthreads();
    const int4* dst4 = (const int4*)(p.ei_tv + ET);
    for (int i = rb * 256 + t; i < ET / 4; i += CM_BLK * 256) {
        const int4 d = dst4[i];
        atomicAdd(&hist[d.x >> 1], 1u << ((d.x & 1) * 16));
        atomicAdd(&hist[d.y >> 1], 1u << ((d.y & 1) * 16));
        atomicAdd(&hist[d.z >> 1], 1u << ((d.z & 1) * 16));
        atomicAdd(&hist[d.w >> 1], 1u << ((d.w & 1) * 16));
    }
    __syncthreads();
    const int rot = (rb * 157) % 2500;
    for (int i = t; i < 2500; i += 256) {
        int j = i + rot; if (j >= 2500) j -= 2500;
        const uint32_t v = hist[j];
        const int lo = (int)(v & 0xFFFFu), hi = (int)(v >> 16);
        if (lo) atomicAdd(&p.cnt_m[2 * j], lo);
        if (hi) atomicAdd(&p.cnt_m[2 * j + 1], hi);
    }
}

// ---- cnt_o: XCD-local atomics. Block rb (global blockIdx rb+CM_BLK; CM_BLK
// is a multiple of 8 so rb%8 == blockIdx%8 == XCD on the round-robin mapping)
// owns dst range [(rb&7)*12800, +12800) and scans chunk rb>>3 of 24. Every
// cnt_o cache line only receives atomics from one XCD -> no line ping-pong.
// If the %8 heuristic is wrong this degrades to R6's behavior (perf-only).
__device__ __forceinline__ void cnto_body(const Par p, int rb) {
    const int t = threadIdx.x;
    const unsigned lo = (unsigned)(rb & 7) * 12800u;
    const int chunk = rb >> 3;               // 0..23
    const int4* d4 = (const int4*)(p.ei_log + EL);
    const int nv = EL / 4;                   // 125000
    const int per = (nv + 23) / 24;          // 5209
    const int i0 = chunk * per;
    const int i1 = min(i0 + per, nv);
    for (int i = i0 + t; i < i1; i += 256) {
        const int4 d = d4[i];
        unsigned q;
        q = (unsigned)d.x - lo; if (q < 12800u) atomicAdd(&p.cnt_o[d.x], 1);
        q = (unsigned)d.y - lo; if (q < 12800u) atomicAdd(&p.cnt_o[d.y], 1);
        q = (unsigned)d.z - lo; if (q < 12800u) atomicAdd(&p.cnt_o[d.z], 1);
        q = (unsigned)d.w - lo; if (q < 12800u) atomicAdd(&p.cnt_o[d.w], 1);
    }
}

// ---- GINE via MFMA, occupancy-safe (channels split across waves) ----
// Granule = 256 edges staged once per block (bf16, double-buffered).
// F[256][8]: features + edge-attrs + constant-1 column (bias = W-row KT,
// zero-padded rows contribute 0). Wave w owns channels [32w, 32w+32).
// Output: per-block channel sums atomicAdd'ed into a replicated 128-vector.
// bf16 inputs stage RAW BITS (integer packs only, no f32 round-trip).
template<int FIN, int ED, bool ISF32>
__device__ __forceinline__ void gine_body(
    const int* __restrict__ src, const void* __restrict__ ea,
    const void* __restrict__ x, const void* __restrict__ We,
    const void* __restrict__ be, const void* __restrict__ Wx,
    const void* __restrict__ bx, float* __restrict__ partv,
    int E, int relb, int nblk, uint4* stage /* [2][256] */)
{
    constexpr int KT = FIN + ED;          // bias row at k=KT; KT+1 <= 8
    const int tid = threadIdx.x;
    const int lane = tid & 63;
    const int wv = tid >> 6;
    const int q = lane >> 4;
    const int col = lane & 15;

    // B fragments for this wave's 2 N-tiles; only quad 0 holds nonzeros (K<=7).
    short8 bfr[2];
#pragma unroll
    for (int nt = 0; nt < 2; ++nt) {
        const int ch = wv * 32 + nt * 16 + col;
        short8 s = (short8)0;
#pragma unroll
        for (int j = 0; j < 8; ++j) {
            const int k = q * 8 + j;
            float w = 0.f;
            if (k < FIN)       w = ldf<ISF32>(Wx, k * H + ch);
            else if (k < KT)   w = ldf<ISF32>(We, (k - FIN) * H + ch);
            else if (k == KT)  w = ldf<ISF32>(bx, ch) + ldf<ISF32>(be, ch);
            s[j] = (short)bfbits(w);
        }
        bfr[nt] = s;
    }
    f32x4 acc0 = (f32x4)0.f, acc1 = (f32x4)0.f;
    const f32x4 zero4 = (f32x4)0.f;

    const int G = (E + 255) >> 8;
    const int chunk = (G + nblk - 1) / nblk;
    const int g0 = relb * chunk;
    const int g1 = min(g0 + chunk, G);
    for (int g = g0; g < g1; ++g) {
        const int buf = g & 1;
        const int base = g << 8;
        const int ecnt = min(256, E - base);
        uint4 pk = (uint4){0, 0, 0, 0};
        if (tid < ecnt) {
            const int ej = base + tid;
            const int s = src[ej];
            if constexpr (!ISF32) {
                // raw-bit path: no float conversions at all
                const uint16_t* xb = (const uint16_t*)x;
                const uint16_t* eb = (const uint16_t*)ea;
                if constexpr (FIN == 4) {          // x_o row = 4 bf16 = uint2
                    const uint2 xr = ((const uint2*)x)[s];
                    pk.x = xr.x; pk.y = xr.y;
                } else {                            // FIN == 3
                    const uint32_t x0 = xb[s * 3], x1 = xb[s * 3 + 1], x2 = xb[s * 3 + 2];
                    pk.x = x0 | (x1 << 16);
                    pk.y = x2;                      // high half filled below
                }
                if constexpr (FIN == 3 && ED == 3) {        // gine_a: KT=6
                    const uint32_t e0 = eb[ej * 3], e1 = eb[ej * 3 + 1], e2 = eb[ej * 3 + 2];
                    pk.y |= e0 << 16;
                    pk.z = e1 | (e2 << 16);
                    pk.w = 0x00003F80u;             // f[6]=1.0, f[7]=0
                } else {                             // gine_c: FIN=4, ED=1, KT=5
                    const uint32_t e0 = eb[ej];
                    pk.z = e0 | (0x3F80u << 16);    // f[4]=ea, f[5]=1.0
                    pk.w = 0;
                }
            } else {
                float f[8];
#pragma unroll
                for (int k = 0; k < 8; ++k) f[k] = 0.f;
                if constexpr (FIN == 4) {
                    const float4 xv = ld4<true>(x, s);
                    f[0] = xv.x; f[1] = xv.y; f[2] = xv.z; f[3] = xv.w;
                } else {
#pragma unroll
                    for (int k = 0; k < FIN; ++k) f[k] = ldf<true>(x, s * FIN + k);
                }
#pragma unroll
                for (int k = 0; k < ED; ++k) f[FIN + k] = ldf<true>(ea, ej * ED + k);
                f[KT] = 1.0f;
                pk.x = pack2(f[0], f[1]); pk.y = pack2(f[2], f[3]);
                pk.z = pack2(f[4], f[5]); pk.w = pack2(f[6], f[7]);
            }
        }
        stage[buf * 256 + tid] = pk;
        __syncthreads();   // stage visible; also guards buf reuse (2 bufs)
        const uint4* st = stage + buf * 256;
#pragma unroll 4
        for (int mt = 0; mt < 16; ++mt) {
            union { short8 s; uint4 u; } au;
            au.u = (uint4){0, 0, 0, 0};
            if (lane < 16) au.u = st[mt * 16 + lane];   // exec-masked A-frag
            f32x4 d0 = __builtin_amdgcn_mfma_f32_16x16x32_bf16(au.s, bfr[0], zero4, 0, 0, 0);
            f32x4 d1 = __builtin_amdgcn_mfma_f32_16x16x32_bf16(au.s, bfr[1], zero4, 0, 0, 0);
            acc0 += __builtin_elementwise_max(d0, zero4);
            acc1 += __builtin_elementwise_max(d1, zero4);
        }
    }
    // fold: 4 regs (edge rows) + cross-quad -> channel sums on lanes 0..15
    float v0 = acc0[0] + acc0[1] + acc0[2] + acc0[3];
    v0 += __shfl_xor(v0, 16, 64);
    v0 += __shfl_xor(v0, 32, 64);
    float v1 = acc1[0] + acc1[1] + acc1[2] + acc1[3];
    v1 += __shfl_xor(v1, 16, 64);
    v1 += __shfl_xor(v1, 32, 64);
    if (lane < 16) {
        atomicAdd(&partv[wv * 32 + col], v0);
        atomicAdd(&partv[wv * 32 + 16 + col], v1);
    }
}

// ---- component sums of x over nodes ----
template<int FIN, bool ISF32>
__device__ __forceinline__ void mean_body(
    const void* __restrict__ x, float* __restrict__ partv, int N,
    int relb, int nblk, float* lds)
{
    const int stride = nblk * 256;
    float acc[FIN];
#pragma unroll
    for (int k = 0; k < FIN; ++k) acc[k] = 0.f;
    for (int n = relb * 256 + threadIdx.x; n < N; n += stride) {
        if constexpr (FIN == 4) {
            const float4 xv = ld4<ISF32>(x, n);
            acc[0] += xv.x; acc[1] += xv.y; acc[2] += xv.z; acc[3] += xv.w;
        } else {
#pragma unroll
            for (int k = 0; k < FIN; ++k) acc[k] += ldf<ISF32>(x, n * FIN + k);
        }
    }
#pragma unroll
    for (int k = 0; k < FIN; ++k) acc[k] = wred(acc[k]);
    if ((threadIdx.x & 63) == 0) {
        const int w = threadIdx.x >> 6;
#pragma unroll
        for (int k = 0; k < 4; ++k) lds[w * 4 + k] = (k < FIN) ? acc[k] : 0.f;
    }
    __syncthreads();
    if (threadIdx.x < 4)
        atomicAdd(&partv[threadIdx.x],
                  lds[threadIdx.x] + lds[4 + threadIdx.x]
                + lds[8 + threadIdx.x] + lds[12 + threadIdx.x]);
}

// ---- SAGE edge reduction, int4-batched ----
template<bool ISF32>
__device__ __forceinline__ void sage_body(
    const void* __restrict__ x, const int* __restrict__ src,
    const int* __restrict__ dst, const int* __restrict__ cnt,
    float* __restrict__ partv, int E, int relb, int nblk, float* lds)
{
    const int tid = threadIdx.x;
    const int nv = E >> 2;
    const int stride = nblk * 256;
    float a0 = 0.f, a1 = 0.f, a2 = 0.f, a3 = 0.f, aw = 0.f;
#pragma unroll 2
    for (int i = relb * 256 + tid; i < nv; i += stride) {
        const int4 s4 = ((const int4*)src)[i];
        const int4 d4 = ((const int4*)dst)[i];
        const int c0 = cnt[d4.x], c1 = cnt[d4.y], c2 = cnt[d4.z], c3 = cnt[d4.w];
        const float4 x0 = ld4<ISF32>(x, s4.x);
        const float4 x1 = ld4<ISF32>(x, s4.y);
        const float4 x2 = ld4<ISF32>(x, s4.z);
        const float4 x3 = ld4<ISF32>(x, s4.w);
        const float i0 = __builtin_amdgcn_rcpf((float)(c0 > 0 ? c0 : 1));
        const float i1 = __builtin_amdgcn_rcpf((float)(c1 > 0 ? c1 : 1));
        const float i2 = __builtin_amdgcn_rcpf((float)(c2 > 0 ? c2 : 1));
        const float i3 = __builtin_amdgcn_rcpf((float)(c3 > 0 ? c3 : 1));
        a0 = fmaf(i0, x0.x, a0); a1 = fmaf(i0, x0.y, a1); a2 = fmaf(i0, x0.z, a2); a3 = fmaf(i0, x0.w, a3); aw += i0;
        a0 = fmaf(i1, x1.x, a0); a1 = fmaf(i1, x1.y, a1); a2 = fmaf(i1, x1.z, a2); a3 = fmaf(i1, x1.w, a3); aw += i1;
        a0 = fmaf(i2, x2.x, a0); a1 = fmaf(i2, x2.y, a1); a2 = fmaf(i2, x2.z, a2); a3 = fmaf(i2, x2.w, a3); aw += i2;
        a0 = fmaf(i3, x3.x, a0); a1 = fmaf(i3, x3.y, a1); a2 = fmaf(i3, x3.z, a2); a3 = fmaf(i3, x3.w, a3); aw += i3;
    }
    a0 = wred(a0); a1 = wred(a1); a2 = wred(a2); a3 = wred(a3); aw = wred(aw);
    if ((tid & 63) == 0) {
        float* w5 = lds + (tid >> 6) * 5;
        w5[0] = a0; w5[1] = a1; w5[2] = a2; w5[3] = a3; w5[4] = aw;
    }
    __syncthreads();
    if (tid < 5)
        atomicAdd(&partv[tid], lds[tid] + lds[5 + tid] + lds[10 + tid] + lds[15 + tid]);
}

// ---- warm: stream final-kernel weights into L2/L3 ----
__device__ __forceinline__ void warm_body(const Par p, int rb, bool f32, float* lds) {
    const void* w[6] = {p.Wn_a, p.Wn_c, p.Wl_tv, p.Wr_tv, p.Wl_log, p.Wr_log};
    const uint4* u = (const uint4*)w[rb];
    const int n16 = (f32 ? (H * H * 4) : (H * H * 2)) / 16;
    uint32_t s = 0;
    for (int i = threadIdx.x; i < n16; i += 256) {
        const uint4 v = u[i];
        s ^= v.x ^ v.y ^ v.z ^ v.w;
    }
    lds[threadIdx.x] = (float)(s & 1);
    __syncthreads();
    if (threadIdx.x == 0) {
        float acc = 0.f;
        for (int i = 0; i < 256; ++i) acc += lds[i];
        p.sink[rb] = acc;   // dummy sink, never read
    }
}

// ---- K1 compute roles (after the count blocks): gine_a | gine_c | means | warm ----
template<bool ISF32>
__device__ __forceinline__ void k1_body(const Par p, uint4* stage, float* red, int b) {
    if (b < B_GA) {
        gine_body<3, 3, ISF32>(p.ei_a, p.ea_a, p.x_m, p.We_a, p.be_a, p.Wm, p.bm,
                               p.part_a + (b & 15) * H, EA, b, B_GA, stage);
    } else if (b < B_GA + B_GC) {
        const int rb = b - B_GA;
        gine_body<4, 1, ISF32>(p.ei_c, p.ea_c, p.x_o, p.We_c, p.be_c, p.Wo, p.bo,
                               p.part_c + (rb & 15) * H, EC, rb, B_GC, stage);
    } else if (b < B_GA + B_GC + B_MN) {
        const int rb = b - (B_GA + B_GC);
        if (rb < 8) mean_body<3, ISF32>(p.x_m, p.part_mn_m + (rb & 7) * 4, NM, rb, 8, red);
        else        mean_body<4, ISF32>(p.x_o, p.part_mn_o + ((rb - 8) & 7) * 4, NO, rb - 8, 40, red);
    } else {
        warm_body(p, b - (B_GA + B_GC + B_MN), ISF32, red);
    }
}

// LDS budget: stage 8192 + red 1152 + hist 10000 = 19344 B <= 20480 (8 blocks/CU).
__global__ __launch_bounds__(256, 8) void k1_kernel(const Par p) {
    __shared__ __align__(16) uint4 stage[512];   // 8 KB: double-buffered 256 edges
    __shared__ float red[288];
    __shared__ uint32_t hist[2500];              // 10 KB packed cnt_m histogram
    const int b = blockIdx.x;
    if (b < CM_BLK)          { cntm_body(p, b, hist); return; }
    if (b < CNT_BLOCKS)      { cnto_body(p, b - CM_BLK); return; }
    const int cb = b - CNT_BLOCKS;
    if (*p.flag) k1_body<true >(p, stage, red, cb);
    else         k1_body<false>(p, stage, red, cb);
}

// ---- K2: sage (needs counts; kernel boundary = coherence) ----
__global__ __launch_bounds__(256, 8) void k2_kernel(const Par p) {
    __shared__ float red[288];
    const int b = blockIdx.x;
    const bool f32 = (*p.flag != 0);
    if (b < B_TV) {
        if (f32) sage_body<true >(p.x_o, p.ei_tv, p.ei_tv + ET, p.cnt_m,
                                  p.part_tv + (b & 7) * 8, ET, b, B_TV, red);
        else     sage_body<false>(p.x_o, p.ei_tv, p.ei_tv + ET, p.cnt_m,
                                  p.part_tv + (b & 7) * 8, ET, b, B_TV, red);
    } else {
        const int rb = b - B_TV;
        if (f32) sage_body<true >(p.x_o, p.ei_log, p.ei_log + EL, p.cnt_o,
                                  p.part_lg + (rb & 7) * 8, EL, rb, B_LG, red);
        else     sage_body<false>(p.x_o, p.ei_log, p.ei_log + EL, p.cnt_o,
                                  p.part_lg + (rb & 7) * 8, EL, rb, B_LG, red);
    }
}

// ---- final: 2 blocks. block 0 -> g_m, block 1 -> g_o ----
template<bool ISF32>
__device__ __forceinline__ void final_body(const Par p) {
    __shared__ float vA[H], vB[H], vC[H], vD[H];
    __shared__ float matp[256];
    __shared__ float sc[12];
    const int t = threadIdx.x;

    if (blockIdx.x == 0) {
        // ---- g_m ----
        if (t < 5) {                       // tv scalars a0..a3, aw
            float s = 0.f;
#pragma unroll
            for (int r = 0; r < 8; ++r) s += p.part_tv[r * 8 + t];
            sc[t] = s;
        } else if (t >= 8 && t < 11) {     // machine mean sums
            const int k = t - 8;
            float s = 0.f;
#pragma unroll
            for (int r = 0; r < 8; ++r) s += p.part_mn_m[r * 4 + k];
            sc[5 + k] = s;
        }
        __syncthreads();
        if (t < H) {
            float tv = sc[4] * ldf<ISF32>(p.bo, t);
#pragma unroll
            for (int k = 0; k < 4; ++k)
                tv = fmaf(sc[k], ldf<ISF32>(p.Wo, k * H + t), tv);
            vA[t] = tv * (1.f / NM);       // vtv
            float mhm = ldf<ISF32>(p.bm, t);
#pragma unroll
            for (int k = 0; k < 3; ++k)
                mhm = fmaf(sc[5 + k] * (1.f / NM), ldf<ISF32>(p.Wm, k * H + t), mhm);
            vB[t] = mhm;                   // vmhm
        }
        __syncthreads();
        {
            const int half = t >> 7, tt = t & 127;
            float acc = (half == 0) ? ldf<ISF32>(p.bl_tv, tt) : 0.f;
            const int k0 = half * 64;
#pragma unroll 8
            for (int k = k0; k < k0 + 64; ++k) {
                acc = fmaf(vA[k], ldf<ISF32>(p.Wl_tv, k * H + tt), acc);
                acc = fmaf(vB[k], ldf<ISF32>(p.Wr_tv, k * H + tt), acc);
            }
            matp[t] = acc;
        }
        __syncthreads();
        if (t < H) {
            const float r = matp[t] + matp[t + 128];
            if constexpr (ISF32) ((float*)p.out)[t] = r;
            else                 ((bf16*)p.out)[t] = __float2bfloat16(r);
        }
    } else {
        // ---- g_o ----
        {   // fold replicated channel accumulators
            const int col = t & 127;
            const float* srcp = (t < 128) ? (p.part_a + col) : (p.part_c + col);
            float s = 0.f;
#pragma unroll 8
            for (int r = 0; r < 16; ++r) s += srcp[r * H];
            if (t < 128) vA[col] = s; else vB[col] = s;
        }
        if (t < 5) {                       // log scalars
            float s = 0.f;
#pragma unroll
            for (int r = 0; r < 8; ++r) s += p.part_lg[r * 8 + t];
            sc[t] = s;
        } else if (t >= 8 && t < 12) {     // op mean sums
            const int k = t - 8;
            float s = 0.f;
#pragma unroll
            for (int r = 0; r < 8; ++r) s += p.part_mn_o[r * 4 + k];
            sc[5 + k] = s;
        }
        __syncthreads();
        if (t < H) {
            float mho = ldf<ISF32>(p.bo, t);
#pragma unroll
            for (int k = 0; k < 4; ++k)
                mho = fmaf(sc[5 + k] * (1.f / NO), ldf<ISF32>(p.Wo, k * H + t), mho);
            float lg = sc[4] * ldf<ISF32>(p.bo, t);
#pragma unroll
            for (int k = 0; k < 4; ++k)
                lg = fmaf(sc[k], ldf<ISF32>(p.Wo, k * H + t), lg);
            vD[t] = mho;                   // vmho
            vC[t] = lg * (1.f / NO);       // vlog
            vA[t] = vA[t] * (1.f / NO) + mho;   // GINE-a vector
            vB[t] = vB[t] * (1.f / NO) + mho;   // GINE-c vector
        }
        __syncthreads();
        {
            const int half = t >> 7, tt = t & 127;
            float acc = (half == 0)
                ? ldf<ISF32>(p.bn_a, tt) + ldf<ISF32>(p.bn_c, tt) + ldf<ISF32>(p.bl_log, tt)
                : 0.f;
            const int k0 = half * 64;
#pragma unroll 8
            for (int k = k0; k < k0 + 64; ++k) {
                acc = fmaf(vA[k], ldf<ISF32>(p.Wn_a, k * H + tt), acc);
                acc = fmaf(vB[k], ldf<ISF32>(p.Wn_c, k * H + tt), acc);
                acc = fmaf(vC[k], ldf<ISF32>(p.Wl_log, k * H + tt), acc);
                acc = fmaf(vD[k], ldf<ISF32>(p.Wr_log, k * H + tt), acc);
            }
            matp[t] = acc;
        }
        __syncthreads();
        if (t < H) {
            const float r = (matp[t] + matp[t + 128]) * (1.f / 3.f);
            if constexpr (ISF32) ((float*)p.out)[H + t] = r;
            else                 ((bf16*)p.out)[H + t] = __float2bfloat16(r);
        }
    }
}

__global__ __launch_bounds__(256) void final_kernel(const Par p) {
    if (*p.flag) final_body<true >(p);
    else         final_body<false>(p);
}

extern "C" void kernel_launch(void* const* d_in, const int* in_sizes, int n_in,
                              void* d_out, int out_size, void* d_ws, size_t ws_size,
                              hipStream_t stream) {
    char* ws = (char*)d_ws;
    Par p;
    p.x_m   = d_in[0];  p.x_o   = d_in[1];
    p.ea_a  = d_in[2];  p.ea_c  = d_in[3];
    p.ei_a  = (const int*)d_in[4];
    p.ei_c  = (const int*)d_in[5];
    p.ei_tv = (const int*)d_in[6];
    p.ei_log= (const int*)d_in[7];
    p.Wm = d_in[8];  p.bm = d_in[9];  p.Wo = d_in[10]; p.bo = d_in[11];
    p.Wn_a = d_in[12]; p.bn_a = d_in[13]; p.We_a = d_in[14]; p.be_a = d_in[15];
    p.Wn_c = d_in[16]; p.bn_c = d_in[17]; p.We_c = d_in[18]; p.be_c = d_in[19];
    p.Wl_tv = d_in[20]; p.bl_tv = d_in[21]; p.Wr_tv = d_in[22];
    p.Wl_log = d_in[23]; p.bl_log = d_in[24]; p.Wr_log = d_in[25];

    // Workspace layout (bytes):
    //   [0,       20480)   cnt_m      int[5000] (padded)      } zero range A
    //   [20480,  430080)   cnt_o      int[102400]             }
    //   [430080, 430084)   flag       (written by zero_kernel detect block)
    //   [430592, 438784)   part_a     float[16][128]          } zero range B
    //   [438784, 446976)   part_c     float[16][128]          }
    //   [446976, 447232)   part_tv    float[8][8]             }
    //   [447232, 447488)   part_lg    float[8][8]             }
    //   [447488, 447616)   part_mn_m  float[8][4]             }
    //   [447616, 447744)   part_mn_o  float[8][4]             }
    //   [447744, 447776)   sink                               }
    p.wsbase    = ws;
    p.cnt_m     = (int*)(ws);
    p.cnt_o     = (int*)(ws + 20480);
    p.flagw     = (int*)(ws + 430080);
    p.flag      = p.flagw;
    p.part_a    = (float*)(ws + 430592);
    p.part_c    = (float*)(ws + 438784);
    p.part_tv   = (float*)(ws + 446976);
    p.part_lg   = (float*)(ws + 447232);
    p.part_mn_m = (float*)(ws + 447488);
    p.part_mn_o = (float*)(ws + 447616);
    p.sink      = (float*)(ws + 447744);
    p.out  = d_out;

    zero_kernel<<<Z_BLOCKS, 256, 0, stream>>>(p);     // zero ws + dtype flag
    k1_kernel<<<K1_BLOCKS, 256, 0, stream>>>(p);      // counts ∥ gine ∥ means ∥ warm
    k2_kernel<<<K2_BLOCKS, 256, 0, stream>>>(p);      // sage (reads counts)
    final_kernel<<<2, 256, 0, stream>>>(p);           // mat-vecs + output
}

// Round 10
// 183.214 us; speedup vs baseline: 1.1125x; 1.0057x over previous
//
#include <hip/hip_runtime.h>
#include <hip/hip_bf16.h>
#include <stdint.h>

// Problem constants (from reference)
#define H   128
#define NM  5000
#define NO  100000
#define EA  1000000
#define EC  500000
#define ET  1000000
#define EL  500000

typedef __hip_bfloat16 bf16;
typedef float f32x4 __attribute__((ext_vector_type(4)));
typedef short short8 __attribute__((ext_vector_type(8)));

// R10 = R9 (best, 184.3) minus one dispatch: final fused into K2 as two
// independent arrival-gated tails.
//   Z  : zero workspace + dtype flag
//   K1 : count_m | count_o | gine_a | gine_c | means | warm   (counts hidden)
//   K2 : sage_tv | sage_log + {last tv block -> g_m tail, last log block ->
//        g_o tail}. g_m depends ONLY on sage_tv partials (+K1 data, visible
//        across the kernel boundary); g_o ONLY on sage_log partials (+K1).
//        Per-relation arrival trees make each tail wait for exactly its
//        dependency; the two tails run in parallel on different blocks.
#define CM_BLK 32
#define CO_BLK 192                  // 8 ranges x 24 chunks
#define CNT_BLOCKS (CM_BLK + CO_BLK)                    // 224 (mult of 8)
#define B_GA 1024
#define B_GC 512
#define B_MN 48
#define B_WM 6
#define K1_BLOCKS (CNT_BLOCKS + B_GA + B_GC + B_MN + B_WM)   // 1814 <= 2048 slots
#define B_TV 512
#define B_LG 256
#define K2_BLOCKS (B_TV + B_LG)

// zero kernel geometry: range A=[0,430080) cnt arrays, B=[430592,447840)
// parts + arrival counters. flag at 430080 sits in the gap (detect block).
#define ZA_U4 26880
#define ZB_OFF 430592
#define ZB_U4 1078
#define Z_BLOCKS 66

struct Par {
    const void *x_m, *x_o, *ea_a, *ea_c;
    const int *ei_a, *ei_c, *ei_tv, *ei_log;
    const void *Wm, *bm, *Wo, *bo;
    const void *Wn_a, *bn_a, *We_a, *be_a;
    const void *Wn_c, *bn_c, *We_c, *be_c;
    const void *Wl_tv, *bl_tv, *Wr_tv, *Wl_log, *bl_log, *Wr_log;
    int *cnt_m, *cnt_o;
    float *part_a, *part_c;        // [16][128] replicated accumulators
    float *part_tv, *part_lg;      // [8][8]
    float *part_mn_m, *part_mn_o;  // [8][4]
    float *sink;
    int *tv_sub, *tv_root;         // arrival tree: sage_tv (8 groups of 64)
    int *lg_sub, *lg_root;         // arrival tree: sage_log (4 groups of 64)
    char *wsbase;
    int *flagw;
    const int *flag;
    void *out;
};

// ---- dtype-flexible loads ----
template<bool ISF32>
__device__ __forceinline__ float ldf(const void* p, int i) {
    if constexpr (ISF32) return ((const float*)p)[i];
    else                 return __bfloat162float(((const bf16*)p)[i]);
}

__device__ __forceinline__ float bflo(uint32_t v) {
    union { uint32_t u; float f; } c; c.u = v << 16; return c.f;
}
__device__ __forceinline__ float bfhi(uint32_t v) {
    union { uint32_t u; float f; } c; c.u = v & 0xFFFF0000u; return c.f;
}

__device__ __forceinline__ uint32_t pack2(float a, float b) {
    union { bf16 h; uint16_t u; } ca, cb;
    ca.h = __float2bfloat16(a); cb.h = __float2bfloat16(b);
    return (uint32_t)ca.u | ((uint32_t)cb.u << 16);
}

__device__ __forceinline__ uint16_t bfbits(float a) {
    union { bf16 h; uint16_t u; } c; c.h = __float2bfloat16(a); return c.u;
}

template<bool ISF32>
__device__ __forceinline__ float4 ld4(const void* p, int row) {
    if constexpr (ISF32) return ((const float4*)p)[row];
    else {
        const uint2 t = ((const uint2*)p)[row];
        float4 r; r.x = bflo(t.x); r.y = bfhi(t.x); r.z = bflo(t.y); r.w = bfhi(t.y);
        return r;
    }
}

__device__ __forceinline__ float wred(float v) {
#pragma unroll
    for (int o = 32; o; o >>= 1) v += __shfl_down(v, o, 64);
    return v;
}

// coherent read of a value produced by device atomics on another XCD within
// the SAME kernel: atomicAdd(p,0) round-trips through the coherence point.
__device__ __forceinline__ float ald(float* p) { return atomicAdd(p, 0.0f); }

// ---- Z: zero workspace + dtype-detect flag ----
__global__ __launch_bounds__(256) void zero_kernel(const Par p) {
    const int t = threadIdx.x;
    const int b = blockIdx.x;
    const uint4 z = (uint4){0, 0, 0, 0};
    if (b < 64) {
        uint4* a = (uint4*)p.wsbase;
        for (int i = b * 256 + t; i < ZA_U4; i += 64 * 256) a[i] = z;
    } else if (b == 64) {
        uint4* bp = (uint4*)(p.wsbase + ZB_OFF);
        for (int i = t; i < ZB_U4; i += 256) bp[i] = z;
    } else {
        // dtype detect: f32 inputs show 0xFF exponent-field patterns in the
        // mantissa-low u16 halves; bf16 N(0,1) never does.
        __shared__ int fl;
        if (t == 0) fl = 0;
        __syncthreads();
        int local = 0;
        const uint16_t* xm = (const uint16_t*)p.x_m;
        for (int i = t; i < 15000; i += 256)
            if (((xm[i] >> 7) & 0xFF) == 0xFF) local = 1;
        if (local) atomicOr(&fl, 1);
        __syncthreads();
        if (t == 0) *p.flagw = fl;
    }
}

// ---- cnt_m: LDS-private histogram, 2x16-bit packed counters (10 KB).
// int4 scan; rotated flush so concurrent blocks hit disjoint address ranges.
__device__ __forceinline__ void cntm_body(const Par p, int rb, uint32_t* hist /*2500*/) {
    const int t = threadIdx.x;
    for (int i = t; i < 2500; i += 256) hist[i] = 0;
    __syncthreads();
    const int4* dst4 = (const int4*)(p.ei_tv + ET);
    for (int i = rb * 256 + t; i < ET / 4; i += CM_BLK * 256) {
        const int4 d = dst4[i];
        atomicAdd(&hist[d.x >> 1], 1u << ((d.x & 1) * 16));
        atomicAdd(&hist[d.y >> 1], 1u << ((d.y & 1) * 16));
        atomicAdd(&hist[d.z >> 1], 1u << ((d.z & 1) * 16));
        atomicAdd(&hist[d.w >> 1], 1u << ((d.w & 1) * 16));
    }
    __syncthreads();
    const int rot = (rb * 157) % 2500;
    for (int i = t; i < 2500; i += 256) {
        int j = i + rot; if (j >= 2500) j -= 2500;
        const uint32_t v = hist[j];
        const int lo = (int)(v & 0xFFFFu), hi = (int)(v >> 16);
        if (lo) atomicAdd(&p.cnt_m[2 * j], lo);
        if (hi) atomicAdd(&p.cnt_m[2 * j + 1], hi);
    }
}

// ---- cnt_o: XCD-local atomics (R9 win: no cross-XCD line ping-pong).
// Block rb owns dst range [(rb&7)*12800,+12800), scans chunk rb>>3 of 24.
__device__ __forceinline__ void cnto_body(const Par p, int rb) {
    const int t = threadIdx.x;
    const unsigned lo = (unsigned)(rb & 7) * 12800u;
    const int chunk = rb >> 3;               // 0..23
    const int4* d4 = (const int4*)(p.ei_log + EL);
    const int nv = EL / 4;                   // 125000
    const int per = (nv + 23) / 24;          // 5209
    const int i0 = chunk * per;
    const int i1 = min(i0 + per, nv);
    for (int i = i0 + t; i < i1; i += 256) {
        const int4 d = d4[i];
        unsigned q;
        q = (unsigned)d.x - lo; if (q < 12800u) atomicAdd(&p.cnt_o[d.x], 1);
        q = (unsigned)d.y - lo; if (q < 12800u) atomicAdd(&p.cnt_o[d.y], 1);
        q = (unsigned)d.z - lo; if (q < 12800u) atomicAdd(&p.cnt_o[d.z], 1);
        q = (unsigned)d.w - lo; if (q < 12800u) atomicAdd(&p.cnt_o[d.w], 1);
    }
}

// ---- GINE via MFMA (channels split across waves); raw-bit bf16 staging ----
template<int FIN, int ED, bool ISF32>
__device__ __forceinline__ void gine_body(
    const int* __restrict__ src, const void* __restrict__ ea,
    const void* __restrict__ x, const void* __restrict__ We,
    const void* __restrict__ be, const void* __restrict__ Wx,
    const void* __restrict__ bx, float* __restrict__ partv,
    int E, int relb, int nblk, uint4* stage /* [2][256] */)
{
    constexpr int KT = FIN + ED;          // bias row at k=KT; KT+1 <= 8
    const int tid = threadIdx.x;
    const int lane = tid & 63;
    const int wv = tid >> 6;
    const int q = lane >> 4;
    const int col = lane & 15;

    short8 bfr[2];
#pragma unroll
    for (int nt = 0; nt < 2; ++nt) {
        const int ch = wv * 32 + nt * 16 + col;
        short8 s = (short8)0;
#pragma unroll
        for (int j = 0; j < 8; ++j) {
            const int k = q * 8 + j;
            float w = 0.f;
            if (k < FIN)       w = ldf<ISF32>(Wx, k * H + ch);
            else if (k < KT)   w = ldf<ISF32>(We, (k - FIN) * H + ch);
            else if (k == KT)  w = ldf<ISF32>(bx, ch) + ldf<ISF32>(be, ch);
            s[j] = (short)bfbits(w);
        }
        bfr[nt] = s;
    }
    f32x4 acc0 = (f32x4)0.f, acc1 = (f32x4)0.f;
    const f32x4 zero4 = (f32x4)0.f;

    const int G = (E + 255) >> 8;
    const int chunk = (G + nblk - 1) / nblk;
    const int g0 = relb * chunk;
    const int g1 = min(g0 + chunk, G);
    for (int g = g0; g < g1; ++g) {
        const int buf = g & 1;
        const int base = g << 8;
        const int ecnt = min(256, E - base);
        uint4 pk = (uint4){0, 0, 0, 0};
        if (tid < ecnt) {
            const int ej = base + tid;
            const int s = src[ej];
            if constexpr (!ISF32) {
                const uint16_t* xb = (const uint16_t*)x;
                const uint16_t* eb = (const uint16_t*)ea;
                if constexpr (FIN == 4) {          // x_o row = 4 bf16 = uint2
                    const uint2 xr = ((const uint2*)x)[s];
                    pk.x = xr.x; pk.y = xr.y;
                } else {                            // FIN == 3
                    const uint32_t x0 = xb[s * 3], x1 = xb[s * 3 + 1], x2 = xb[s * 3 + 2];
                    pk.x = x0 | (x1 << 16);
                    pk.y = x2;
                }
                if constexpr (FIN == 3 && ED == 3) {        // gine_a: KT=6
                    const uint32_t e0 = eb[ej * 3], e1 = eb[ej * 3 + 1], e2 = eb[ej * 3 + 2];
                    pk.y |= e0 << 16;
                    pk.z = e1 | (e2 << 16);
                    pk.w = 0x00003F80u;             // f[6]=1.0, f[7]=0
                } else {                             // gine_c: FIN=4, ED=1, KT=5
                    const uint32_t e0 = eb[ej];
                    pk.z = e0 | (0x3F80u << 16);    // f[4]=ea, f[5]=1.0
                    pk.w = 0;
                }
            } else {
                float f[8];
#pragma unroll
                for (int k = 0; k < 8; ++k) f[k] = 0.f;
                if constexpr (FIN == 4) {
                    const float4 xv = ld4<true>(x, s);
                    f[0] = xv.x; f[1] = xv.y; f[2] = xv.z; f[3] = xv.w;
                } else {
#pragma unroll
                    for (int k = 0; k < FIN; ++k) f[k] = ldf<true>(x, s * FIN + k);
                }
#pragma unroll
                for (int k = 0; k < ED; ++k) f[FIN + k] = ldf<true>(ea, ej * ED + k);
                f[KT] = 1.0f;
                pk.x = pack2(f[0], f[1]); pk.y = pack2(f[2], f[3]);
                pk.z = pack2(f[4], f[5]); pk.w = pack2(f[6], f[7]);
            }
        }
        stage[buf * 256 + tid] = pk;
        __syncthreads();   // stage visible; also guards buf reuse (2 bufs)
        const uint4* st = stage + buf * 256;
#pragma unroll 4
        for (int mt = 0; mt < 16; ++mt) {
            union { short8 s; uint4 u; } au;
            au.u = (uint4){0, 0, 0, 0};
            if (lane < 16) au.u = st[mt * 16 + lane];   // exec-masked A-frag
            f32x4 d0 = __builtin_amdgcn_mfma_f32_16x16x32_bf16(au.s, bfr[0], zero4, 0, 0, 0);
            f32x4 d1 = __builtin_amdgcn_mfma_f32_16x16x32_bf16(au.s, bfr[1], zero4, 0, 0, 0);
            acc0 += __builtin_elementwise_max(d0, zero4);
            acc1 += __builtin_elementwise_max(d1, zero4);
        }
    }
    float v0 = acc0[0] + acc0[1] + acc0[2] + acc0[3];
    v0 += __shfl_xor(v0, 16, 64);
    v0 += __shfl_xor(v0, 32, 64);
    float v1 = acc1[0] + acc1[1] + acc1[2] + acc1[3];
    v1 += __shfl_xor(v1, 16, 64);
    v1 += __shfl_xor(v1, 32, 64);
    if (lane < 16) {
        atomicAdd(&partv[wv * 32 + col], v0);
        atomicAdd(&partv[wv * 32 + 16 + col], v1);
    }
}

// ---- component sums of x over nodes ----
template<int FIN, bool ISF32>
__device__ __forceinline__ void mean_body(
    const void* __restrict__ x, float* __restrict__ partv, int N,
    int relb, int nblk, float* lds)
{
    const int stride = nblk * 256;
    float acc[FIN];
#pragma unroll
    for (int k = 0; k < FIN; ++k) acc[k] = 0.f;
    for (int n = relb * 256 + threadIdx.x; n < N; n += stride) {
        if constexpr (FIN == 4) {
            const float4 xv = ld4<ISF32>(x, n);
            acc[0] += xv.x; acc[1] += xv.y; acc[2] += xv.z; acc[3] += xv.w;
        } else {
#pragma unroll
            for (int k = 0; k < FIN; ++k) acc[k] += ldf<ISF32>(x, n * FIN + k);
        }
    }
#pragma unroll
    for (int k = 0; k < FIN; ++k) acc[k] = wred(acc[k]);
    if ((threadIdx.x & 63) == 0) {
        const int w = threadIdx.x >> 6;
#pragma unroll
        for (int k = 0; k < 4; ++k) lds[w * 4 + k] = (k < FIN) ? acc[k] : 0.f;
    }
    __syncthreads();
    if (threadIdx.x < 4)
        atomicAdd(&partv[threadIdx.x],
                  lds[threadIdx.x] + lds[4 + threadIdx.x]
                + lds[8 + threadIdx.x] + lds[12 + threadIdx.x]);
}

// ---- SAGE edge reduction, int4-batched ----
template<bool ISF32>
__device__ __forceinline__ void sage_body(
    const void* __restrict__ x, const int* __restrict__ src,
    const int* __restrict__ dst, const int* __restrict__ cnt,
    float* __restrict__ partv, int E, int relb, int nblk, float* lds)
{
    const int tid = threadIdx.x;
    const int nv = E >> 2;
    const int stride = nblk * 256;
    float a0 = 0.f, a1 = 0.f, a2 = 0.f, a3 = 0.f, aw = 0.f;
#pragma unroll 2
    for (int i = relb * 256 + tid; i < nv; i += stride) {
        const int4 s4 = ((const int4*)src)[i];
        const int4 d4 = ((const int4*)dst)[i];
        const int c0 = cnt[d4.x], c1 = cnt[d4.y], c2 = cnt[d4.z], c3 = cnt[d4.w];
        const float4 x0 = ld4<ISF32>(x, s4.x);
        const float4 x1 = ld4<ISF32>(x, s4.y);
        const float4 x2 = ld4<ISF32>(x, s4.z);
        const float4 x3 = ld4<ISF32>(x, s4.w);
        const float i0 = __builtin_amdgcn_rcpf((float)(c0 > 0 ? c0 : 1));
        const float i1 = __builtin_amdgcn_rcpf((float)(c1 > 0 ? c1 : 1));
        const float i2 = __builtin_amdgcn_rcpf((float)(c2 > 0 ? c2 : 1));
        const float i3 = __builtin_amdgcn_rcpf((float)(c3 > 0 ? c3 : 1));
        a0 = fmaf(i0, x0.x, a0); a1 = fmaf(i0, x0.y, a1); a2 = fmaf(i0, x0.z, a2); a3 = fmaf(i0, x0.w, a3); aw += i0;
        a0 = fmaf(i1, x1.x, a0); a1 = fmaf(i1, x1.y, a1); a2 = fmaf(i1, x1.z, a2); a3 = fmaf(i1, x1.w, a3); aw += i1;
        a0 = fmaf(i2, x2.x, a0); a1 = fmaf(i2, x2.y, a1); a2 = fmaf(i2, x2.z, a2); a3 = fmaf(i2, x2.w, a3); aw += i2;
        a0 = fmaf(i3, x3.x, a0); a1 = fmaf(i3, x3.y, a1); a2 = fmaf(i3, x3.z, a2); a3 = fmaf(i3, x3.w, a3); aw += i3;
    }
    a0 = wred(a0); a1 = wred(a1); a2 = wred(a2); a3 = wred(a3); aw = wred(aw);
    if ((tid & 63) == 0) {
        float* w5 = lds + (tid >> 6) * 5;
        w5[0] = a0; w5[1] = a1; w5[2] = a2; w5[3] = a3; w5[4] = aw;
    }
    __syncthreads();
    if (tid < 5)
        atomicAdd(&partv[tid], lds[tid] + lds[5 + tid] + lds[10 + tid] + lds[15 + tid]);
}

// ---- warm: stream final-phase weights into L2/L3 ----
__device__ __forceinline__ void warm_body(const Par p, int rb, bool f32, float* lds) {
    const void* w[6] = {p.Wn_a, p.Wn_c, p.Wl_tv, p.Wr_tv, p.Wl_log, p.Wr_log};
    const uint4* u = (const uint4*)w[rb];
    const int n16 = (f32 ? (H * H * 4) : (H * H * 2)) / 16;
    uint32_t s = 0;
    for (int i = threadIdx.x; i < n16; i += 256) {
        const uint4 v = u[i];
        s ^= v.x ^ v.y ^ v.z ^ v.w;
    }
    lds[threadIdx.x] = (float)(s & 1);
    __syncthreads();
    if (threadIdx.x == 0) {
        float acc = 0.f;
        for (int i = 0; i < 256; ++i) acc += lds[i];
        p.sink[rb] = acc;   // dummy sink, never read
    }
}

// ---- K1 compute roles (after the count blocks): gine_a | gine_c | means | warm ----
template<bool ISF32>
__device__ __forceinline__ void k1_body(const Par p, uint4* stage, float* red, int b) {
    if (b < B_GA) {
        gine_body<3, 3, ISF32>(p.ei_a, p.ea_a, p.x_m, p.We_a, p.be_a, p.Wm, p.bm,
                               p.part_a + (b & 15) * H, EA, b, B_GA, stage);
    } else if (b < B_GA + B_GC) {
        const int rb = b - B_GA;
        gine_body<4, 1, ISF32>(p.ei_c, p.ea_c, p.x_o, p.We_c, p.be_c, p.Wo, p.bo,
                               p.part_c + (rb & 15) * H, EC, rb, B_GC, stage);
    } else if (b < B_GA + B_GC + B_MN) {
        const int rb = b - (B_GA + B_GC);
        if (rb < 8) mean_body<3, ISF32>(p.x_m, p.part_mn_m + (rb & 7) * 4, NM, rb, 8, red);
        else        mean_body<4, ISF32>(p.x_o, p.part_mn_o + ((rb - 8) & 7) * 4, NO, rb - 8, 40, red);
    } else {
        warm_body(p, b - (B_GA + B_GC + B_MN), ISF32, red);
    }
}

// LDS budget: stage 8192 + red 1152 + hist 10000 = 19344 B <= 20480 (8 blocks/CU).
__global__ __launch_bounds__(256, 8) void k1_kernel(const Par p) {
    __shared__ __align__(16) uint4 stage[512];   // 8 KB: double-buffered 256 edges
    __shared__ float red[288];
    __shared__ uint32_t hist[2500];              // 10 KB packed cnt_m histogram
    const int b = blockIdx.x;
    if (b < CM_BLK)          { cntm_body(p, b, hist); return; }
    if (b < CNT_BLOCKS)      { cnto_body(p, b - CM_BLK); return; }
    const int cb = b - CNT_BLOCKS;
    if (*p.flag) k1_body<true >(p, stage, red, cb);
    else         k1_body<false>(p, stage, red, cb);
}

// ---- g_m tail: run by the LAST sage_tv block. Depends only on part_tv
// (same-kernel atomics -> ald) + K1 data (kernel boundary -> plain loads).
template<bool ISF32>
__device__ void gm_tail(const Par p, float* vA, float* vB, float* matp, float* sc) {
    const int t = threadIdx.x;
    if (t < 5) {                       // tv scalars a0..a3, aw (ald: same-kernel)
        float s = 0.f;
#pragma unroll
        for (int r = 0; r < 8; ++r) s += ald(p.part_tv + r * 8 + t);
        sc[t] = s;
    } else if (t >= 8 && t < 11) {     // machine mean sums (K1: plain)
        const int k = t - 8;
        float s = 0.f;
#pragma unroll
        for (int r = 0; r < 8; ++r) s += p.part_mn_m[r * 4 + k];
        sc[5 + k] = s;
    }
    __syncthreads();
    if (t < H) {
        float tv = sc[4] * ldf<ISF32>(p.bo, t);
#pragma unroll
        for (int k = 0; k < 4; ++k)
            tv = fmaf(sc[k], ldf<ISF32>(p.Wo, k * H + t), tv);
        vA[t] = tv * (1.f / NM);       // vtv
        float mhm = ldf<ISF32>(p.bm, t);
#pragma unroll
        for (int k = 0; k < 3; ++k)
            mhm = fmaf(sc[5 + k] * (1.f / NM), ldf<ISF32>(p.Wm, k * H + t), mhm);
        vB[t] = mhm;                   // vmhm
    }
    __syncthreads();
    {
        const int half = t >> 7, tt = t & 127;
        float acc = (half == 0) ? ldf<ISF32>(p.bl_tv, tt) : 0.f;
        const int k0 = half * 64;
#pragma unroll 8
        for (int k = k0; k < k0 + 64; ++k) {
            acc = fmaf(vA[k], ldf<ISF32>(p.Wl_tv, k * H + tt), acc);
            acc = fmaf(vB[k], ldf<ISF32>(p.Wr_tv, k * H + tt), acc);
        }
        matp[t] = acc;
    }
    __syncthreads();
    if (t < H) {
        const float r = matp[t] + matp[t + 128];
        if constexpr (ISF32) ((float*)p.out)[t] = r;
        else                 ((bf16*)p.out)[t] = __float2bfloat16(r);
    }
}

// ---- g_o tail: run by the LAST sage_log block. Depends only on part_lg
// (ald) + K1 data: part_a/c, part_mn_o (plain loads across kernel boundary).
template<bool ISF32>
__device__ void go_tail(const Par p, float* vA, float* vB, float* vC, float* vD,
                        float* matp, float* sc) {
    const int t = threadIdx.x;
    {   // fold replicated channel accumulators (K1 data: plain)
        const int col = t & 127;
        const float* srcp = (t < 128) ? (p.part_a + col) : (p.part_c + col);
        float s = 0.f;
#pragma unroll 8
        for (int r = 0; r < 16; ++r) s += srcp[r * H];
        if (t < 128) vA[col] = s; else vB[col] = s;
    }
    if (t < 5) {                       // log scalars (ald: same-kernel)
        float s = 0.f;
#pragma unroll
        for (int r = 0; r < 8; ++r) s += ald(p.part_lg + r * 8 + t);
        sc[t] = s;
    } else if (t >= 8 && t < 12) {     // op mean sums (K1: plain)
        const int k = t - 8;
        float s = 0.f;
#pragma unroll
        for (int r = 0; r < 8; ++r) s += p.part_mn_o[r * 4 + k];
        sc[5 + k] = s;
    }
    __syncthreads();
    if (t < H) {
        float mho = ldf<ISF32>(p.bo, t);
#pragma unroll
        for (int k = 0; k < 4; ++k)
            mho = fmaf(sc[5 + k] * (1.f / NO), ldf<ISF32>(p.Wo, k * H + t), mho);
        float lg = sc[4] * ldf<ISF32>(p.bo, t);
#pragma unroll
        for (int k = 0; k < 4; ++k)
            lg = fmaf(sc[k], ldf<ISF32>(p.Wo, k * H + t), lg);
        vD[t] = mho;                   // vmho
        vC[t] = lg * (1.f / NO);       // vlog
        vA[t] = vA[t] * (1.f / NO) + mho;   // GINE-a vector
        vB[t] = vB[t] * (1.f / NO) + mho;   // GINE-c vector
    }
    __syncthreads();
    {
        const int half = t >> 7, tt = t & 127;
        float acc = (half == 0)
            ? ldf<ISF32>(p.bn_a, tt) + ldf<ISF32>(p.bn_c, tt) + ldf<ISF32>(p.bl_log, tt)
            : 0.f;
        const int k0 = half * 64;
#pragma unroll 8
        for (int k = k0; k < k0 + 64; ++k) {
            acc = fmaf(vA[k], ldf<ISF32>(p.Wn_a, k * H + tt), acc);
            acc = fmaf(vB[k], ldf<ISF32>(p.Wn_c, k * H + tt), acc);
            acc = fmaf(vC[k], ldf<ISF32>(p.Wl_log, k * H + tt), acc);
            acc = fmaf(vD[k], ldf<ISF32>(p.Wr_log, k * H + tt), acc);
        }
        matp[t] = acc;
    }
    __syncthreads();
    if (t < H) {
        const float r = (matp[t] + matp[t + 128]) * (1.f / 3.f);
        if constexpr (ISF32) ((float*)p.out)[H + t] = r;
        else                 ((bf16*)p.out)[H + t] = __float2bfloat16(r);
    }
}

// ---- K2: sage + per-relation arrival-gated tails. No __threadfence: the
// __syncthreads before arrival drains vmcnt (compiler emits s_waitcnt
// vmcnt(0) before s_barrier), so partv atomics have completed at the
// coherence point (R3-proven pattern). Two-level trees bound same-address
// contention to <=64 per counter.
__global__ __launch_bounds__(256) void k2_kernel(const Par p) {
    __shared__ float red[288];
    __shared__ float vA[H], vB[H], vC[H], vD[H];
    __shared__ float matp[256];
    __shared__ float sc[12];
    __shared__ int role;
    const int b = blockIdx.x;
    const bool f32 = (*p.flag != 0);
    if (b < B_TV) {
        if (f32) sage_body<true >(p.x_o, p.ei_tv, p.ei_tv + ET, p.cnt_m,
                                  p.part_tv + (b & 7) * 8, ET, b, B_TV, red);
        else     sage_body<false>(p.x_o, p.ei_tv, p.ei_tv + ET, p.cnt_m,
                                  p.part_tv + (b & 7) * 8, ET, b, B_TV, red);
    } else {
        const int rb = b - B_TV;
        if (f32) sage_body<true >(p.x_o, p.ei_log, p.ei_log + EL, p.cnt_o,
                                  p.part_lg + (rb & 7) * 8, EL, rb, B_LG, red);
        else     sage_body<false>(p.x_o, p.ei_log, p.ei_log + EL, p.cnt_o,
                                  p.part_lg + (rb & 7) * 8, EL, rb, B_LG, red);
    }
    __syncthreads();   // drains vmcnt: this block's partv atomics complete
    if (threadIdx.x == 0) {
        role = 0;
        if (b < B_TV) {
            const int g = b >> 6;                          // 8 groups of 64
            if (atomicAdd(&p.tv_sub[g], 1) == 63)
                if (atomicAdd(p.tv_root, 1) == 7) role = 1;    // last tv -> g_m
        } else {
            const int g = (b - B_TV) >> 6;                 // 4 groups of 64
            if (atomicAdd(&p.lg_sub[g], 1) == 63)
                if (atomicAdd(p.lg_root, 1) == 3) role = 2;    // last log -> g_o
        }
    }
    __syncthreads();
    if (role == 1) {
        if (f32) gm_tail<true >(p, vA, vB, matp, sc);
        else     gm_tail<false>(p, vA, vB, matp, sc);
    } else if (role == 2) {
        if (f32) go_tail<true >(p, vA, vB, vC, vD, matp, sc);
        else     go_tail<false>(p, vA, vB, vC, vD, matp, sc);
    }
}

extern "C" void kernel_launch(void* const* d_in, const int* in_sizes, int n_in,
                              void* d_out, int out_size, void* d_ws, size_t ws_size,
                              hipStream_t stream) {
    char* ws = (char*)d_ws;
    Par p;
    p.x_m   = d_in[0];  p.x_o   = d_in[1];
    p.ea_a  = d_in[2];  p.ea_c  = d_in[3];
    p.ei_a  = (const int*)d_in[4];
    p.ei_c  = (const int*)d_in[5];
    p.ei_tv = (const int*)d_in[6];
    p.ei_log= (const int*)d_in[7];
    p.Wm = d_in[8];  p.bm = d_in[9];  p.Wo = d_in[10]; p.bo = d_in[11];
    p.Wn_a = d_in[12]; p.bn_a = d_in[13]; p.We_a = d_in[14]; p.be_a = d_in[15];
    p.Wn_c = d_in[16]; p.bn_c = d_in[17]; p.We_c = d_in[18]; p.be_c = d_in[19];
    p.Wl_tv = d_in[20]; p.bl_tv = d_in[21]; p.Wr_tv = d_in[22];
    p.Wl_log = d_in[23]; p.bl_log = d_in[24]; p.Wr_log = d_in[25];

    // Workspace layout (bytes):
    //   [0,       20480)   cnt_m      int[5000] (padded)      } zero range A
    //   [20480,  430080)   cnt_o      int[102400]             }
    //   [430080, 430084)   flag       (written by zero_kernel detect block)
    //   [430592, 438784)   part_a     float[16][128]          } zero range B
    //   [438784, 446976)   part_c     float[16][128]          }
    //   [446976, 447232)   part_tv    float[8][8]             }
    //   [447232, 447488)   part_lg    float[8][8]             }
    //   [447488, 447616)   part_mn_m  float[8][4]             }
    //   [447616, 447744)   part_mn_o  float[8][4]             }
    //   [447744, 447776)   sink                               }
    //   [447776, 447808)   tv_sub     int[8]                  }
    //   [447808, 447812)   tv_root                            }
    //   [447812, 447828)   lg_sub     int[4]                  }
    //   [447828, 447832)   lg_root                            }
    p.wsbase    = ws;
    p.cnt_m     = (int*)(ws);
    p.cnt_o     = (int*)(ws + 20480);
    p.flagw     = (int*)(ws + 430080);
    p.flag      = p.flagw;
    p.part_a    = (float*)(ws + 430592);
    p.part_c    = (float*)(ws + 438784);
    p.part_tv   = (float*)(ws + 446976);
    p.part_lg   = (float*)(ws + 447232);
    p.part_mn_m = (float*)(ws + 447488);
    p.part_mn_o = (float*)(ws + 447616);
    p.sink      = (float*)(ws + 447744);
    p.tv_sub    = (int*)(ws + 447776);
    p.tv_root   = (int*)(ws + 447808);
    p.lg_sub    = (int*)(ws + 447812);
    p.lg_root   = (int*)(ws + 447828);
    p.out  = d_out;

    zero_kernel<<<Z_BLOCKS, 256, 0, stream>>>(p);     // zero ws + dtype flag
    k1_kernel<<<K1_BLOCKS, 256, 0, stream>>>(p);      // counts ∥ gine ∥ means ∥ warm
    k2_kernel<<<K2_BLOCKS, 256, 0, stream>>>(p);      // sage + fused final tails
}